// Round 15
// baseline (130.679 us; speedup 1.0000x reference)
//
#include <hip/hip_runtime.h>

// Performer (FAVOR+) attention, MI355X, split-bf16 MFMA.
// B=2 H=8 N=8192 D=64 F=256; rows R = 131072.
// Round 15 (qoK only): 64-row iterations (4 iters/chunk, was 8x32) —
// halves barriers (16->8/chunk), halves STAGEQ/drain events, 4 independent
// dd MFMA chains of ILP. dd processed per row-tile (qa transient) to cap
// registers (~195 peak < 256 @ 2w/EU). Epilogue div -> v_rcp_f32.
// ctxK/stabK/redK/initK unchanged from round 14 (controls).

typedef __bf16 bf16;
typedef __bf16 bf16x8 __attribute__((ext_vector_type(8)));
typedef _Float16 f16;
typedef f16 f16x8 __attribute__((ext_vector_type(8)));
typedef float f32x4 __attribute__((ext_vector_type(4)));

#define N_    8192
#define BH_   16
#define NRM   0.35355339059327379f   // 64^-0.25
#define RATIO 0.0625f                // 256^-0.5
#define DSC   0.0625f                // 0.5*NRM^2
#define REPS  6.25e-6f               // RATIO*1e-4

#define CTX_W  16
#define KSUM_W (CTX_W + BH_*256*64)     // 262160
#define ZERO_W (KSUM_W + BH_*256)       // 266256
#define SLICE_W 16640                   // 16384 ctx + 256 ksum per (bh,ch)
#define PART_W  ZERO_W                  // partials start here (32*16*16640 w)

static __device__ __forceinline__ unsigned mapmax(float x){
  unsigned u=__float_as_uint(x); return (u&0x80000000u)? ~u : (u|0x80000000u);
}
static __device__ __forceinline__ float unmapmax(unsigned u){
  return __uint_as_float((u&0x80000000u)? (u&0x7fffffffu) : ~u);
}
static __device__ __forceinline__ f32x4 mfma16(bf16x8 a, bf16x8 b, f32x4 c){
  return __builtin_amdgcn_mfma_f32_16x16x32_bf16(a,b,c,0,0,0);
}
static __device__ __forceinline__ f32x4 mfma16h(f16x8 a, f16x8 b, f32x4 c){
  return __builtin_amdgcn_mfma_f32_16x16x32_f16(a,b,c,0,0,0);
}
static __device__ __forceinline__ void ld8(const float* __restrict__ p, float* x){
  float4 a=*(const float4*)p; float4 b=*(const float4*)(p+4);
  x[0]=a.x; x[1]=a.y; x[2]=a.z; x[3]=a.w; x[4]=b.x; x[5]=b.y; x[6]=b.z; x[7]=b.w;
}
static __device__ __forceinline__ void split8(const float* x, bf16x8& h, bf16x8& l){
  #pragma unroll
  for(int i=0;i<8;++i){ bf16 hi=(bf16)x[i]; h[i]=hi; l[i]=(bf16)(x[i]-(float)hi); }
}
static __device__ __forceinline__ void cvt8b(const float* x, bf16x8& h){
  #pragma unroll
  for(int i=0;i<8;++i) h[i]=(bf16)x[i];
}
static __device__ __forceinline__ void cvt8h(const float* x, f16x8& h){
  #pragma unroll
  for(int i=0;i<8;++i) h[i]=(f16)x[i];
}
static __device__ __forceinline__ void gload16(const float* g, float* l){
  __builtin_amdgcn_global_load_lds(
      (const __attribute__((address_space(1))) unsigned*)g,
      (__attribute__((address_space(3))) unsigned*)l, 16, 0, 0);
}
// P-hat (NRM*P) b-fragments, SINGLE bf16 plane: [ft 0..3][ks 0..1]
static __device__ __forceinline__ void load_P_frags1(const float* __restrict__ Pg,
    int fb, int l15, int g, bf16x8 (&pb)[4][2]){
  #pragma unroll
  for(int ft=0;ft<4;++ft)
    #pragma unroll
    for(int ks=0;ks<2;++ks){
      float x[8]; ld8(&Pg[(fb+16*ft+l15)*64+32*ks+8*g],x);
      #pragma unroll
      for(int i=0;i<8;++i) x[i]*=NRM;
      cvt8b(x,pb[ft][ks]);
    }
}

// stage 32 rows x 64 floats from Xg into LDS buf, source XOR-swizzled by
// row&15 so fragment-pattern b128 reads are conflict-free (r9 pattern).
#define STAGE32(Xg, bufptr, n0s) do{                                      \
    int u0_=tid, u1_=tid+256;                                             \
    int r0_=u0_>>4, c0_=u0_&15, r1_=u1_>>4, c1_=u1_&15;                   \
    gload16((Xg)+((n0s)+r0_)*64+((c0_^(r0_&15))<<2), (bufptr)+u0_*4);     \
    gload16((Xg)+((n0s)+r1_)*64+((c1_^(r1_&15))<<2), (bufptr)+u1_*4);     \
  }while(0)
// stage 64 rows x 64 floats (qoK fat iters)
#define STAGE64(Xg, bufptr, n0s) do{                                      \
    _Pragma("unroll")                                                     \
    for(int ii_=0;ii_<4;++ii_){                                           \
      int u_=tid+256*ii_;                                                 \
      int r_=u_>>4, c_=u_&15;                                             \
      gload16((Xg)+((n0s)+r_)*64+((c_^(r_&15))<<2), (bufptr)+u_*4);       \
    }                                                                     \
  }while(0)
// x[8] <- staged row rr, k-chunk ks (two swizzled b128 reads)
#define FRAGREAD(xv, bufptr, rr, ksv) do{                                 \
    int cc0_=(8*(ksv)+2*g)^((rr)&15);                                     \
    int cc1_=cc0_^1;                                                      \
    float4 a_=*(const float4*)((bufptr)+(rr)*64+cc0_*4);                  \
    float4 b_=*(const float4*)((bufptr)+(rr)*64+cc1_*4);                  \
    xv[0]=a_.x; xv[1]=a_.y; xv[2]=a_.z; xv[3]=a_.w;                       \
    xv[4]=b_.x; xv[5]=b_.y; xv[6]=b_.z; xv[7]=b_.w;                       \
  }while(0)

// ---------------- kernels ----------------

__global__ void __launch_bounds__(256) initK(unsigned* ws){
  for(int i=blockIdx.x*256+threadIdx.x;i<ZERO_W;i+=gridDim.x*256) ws[i]=0u;
}

// global max of dd_k (single-f16). grid 512, 4 iters of 64 rows (P amortized).
__global__ void __launch_bounds__(256) stabK(const float* __restrict__ Kg,
                                             const float* __restrict__ Pg,
                                             unsigned* __restrict__ stab_ws){
  __shared__ float red[4];
  int tid=threadIdx.x, w=tid>>6, lane=tid&63, l15=lane&15, g=lane>>4;
  int fb=w*64;
  f16x8 pb[4][2];
  #pragma unroll
  for(int ft=0;ft<4;++ft)
    #pragma unroll
    for(int ks=0;ks<2;++ks){
      float x[8]; ld8(&Pg[(fb+16*ft+l15)*64+32*ks+8*g],x);
      #pragma unroll
      for(int i=0;i<8;++i) x[i]*=NRM;
      cvt8h(x,pb[ft][ks]);
    }
  float m=-3.4e38f;
  long base=(long)blockIdx.x*256;
  f32x4 zero={0.f,0.f,0.f,0.f};
  #pragma unroll 1
  for(int it=0;it<4;++it){
    long row0=base+it*64;
    f16x8 ka[4][2];
    #pragma unroll
    for(int rt=0;rt<4;++rt)
      #pragma unroll
      for(int ks=0;ks<2;++ks){
        float x[8]; ld8(&Kg[(row0+16*rt+l15)*64+32*ks+8*g],x);
        cvt8h(x,ka[rt][ks]);
      }
    f32x4 acc[4][4];
    #pragma unroll
    for(int rt=0;rt<4;++rt)
      #pragma unroll
      for(int ft=0;ft<4;++ft) acc[rt][ft]=zero;
    #pragma unroll
    for(int rt=0;rt<4;++rt)
      #pragma unroll
      for(int ft=0;ft<4;++ft)
        #pragma unroll
        for(int ks=0;ks<2;++ks)
          acc[rt][ft]=mfma16h(ka[rt][ks],pb[ft][ks],acc[rt][ft]);
    #pragma unroll
    for(int rt=0;rt<4;++rt)
      #pragma unroll
      for(int ft=0;ft<4;++ft)
        #pragma unroll
        for(int r=0;r<4;++r) m=fmaxf(m,acc[rt][ft][r]);
  }
  #pragma unroll
  for(int off=1;off<64;off<<=1) m=fmaxf(m,__shfl_xor(m,off));
  if(lane==0) red[w]=m;
  __syncthreads();
  if(tid==0){
    m=fmaxf(fmaxf(red[0],red[1]),fmaxf(red[2],red[3]));
    atomicMax(stab_ws,mapmax(m));
  }
}

// kp + ctx/ksum accumulation. grid = 512: 16 bh * 32 chunks of 256 rows,
// 8 iters. K LDS-staged dbuf; V reg-prefetched; P single bf16; 2-pass dd.
// Epilogue: mode=1 -> plain stores into private partial slice (bh,ch);
// mode=0 -> atomic path. UNCHANGED from round 14.
__global__ void __launch_bounds__(256,2) ctxK(const float* __restrict__ Kg,
    const float* __restrict__ Vg, const float* __restrict__ Pg,
    const unsigned* __restrict__ stab_ws, float* __restrict__ ctx_g,
    float* __restrict__ ksum_g, float* __restrict__ part, int mode){
  __shared__ __align__(16) bf16 kpt_h[256*40];   // 20KB
  __shared__ float kstage[2][2048];              // 2 x 8KB staged K tiles
  int tid=threadIdx.x, w=tid>>6, lane=tid&63, l15=lane&15, g=lane>>4;
  int fb=w*64;
  int bh=blockIdx.x>>5, ch=blockIdx.x&31;
  long rowbase=(long)bh*N_ + ch*256;
  float stab=unmapmax(*stab_ws);
  bf16x8 pb[4][2];
  load_P_frags1(Pg,fb,l15,g,pb);
  f32x4 zero={0.f,0.f,0.f,0.f};
  f32x4 cacc[4][4];
  #pragma unroll
  for(int mt=0;mt<4;++mt)
    #pragma unroll
    for(int et=0;et<4;++et) cacc[mt][et]=zero;
  float ksacc[4]={0.f,0.f,0.f,0.f};
  int cur=0;
  STAGE32(Kg, &kstage[0][0], rowbase);
  __syncthreads();                       // drain staging for iter 0
  #pragma unroll 1
  for(int it=0;it<8;++it){
    long n0=rowbase+it*32;
    long np=(it==7)? rowbase : n0+32;    // last iter: dummy re-stage (harmless)
    STAGE32(Kg, &kstage[cur^1][0], np);  // issue next K tile; lands by barrier
    // V raw prefetch (latency hidden under dd-GEMM + exp)
    float vx[4][8];
    #pragma unroll
    for(int et=0;et<4;++et)
      #pragma unroll
      for(int j=0;j<8;++j) vx[et][j]=Vg[(n0+8*g+j)*64+16*et+l15];
    // K a-frags (split) + row sums of squares, from staged LDS
    bf16x8 ka_h[2][2], ka_l[2][2];
    float dsq[2];
    #pragma unroll
    for(int rt=0;rt<2;++rt){
      float ss=0.f;
      #pragma unroll
      for(int ks=0;ks<2;++ks){
        float x[8]; FRAGREAD(x,&kstage[cur][0],16*rt+l15,ks);
        #pragma unroll
        for(int i=0;i<8;++i) ss=fmaf(x[i],x[i],ss);
        split8(x,ka_h[rt][ks],ka_l[rt][ks]);
      }
      ss+=__shfl_xor(ss,16); ss+=__shfl_xor(ss,32);
      dsq[rt]=DSC*ss;
    }
    // dd = (Kh + Kl) @ P (2-pass; P single bf16)
    f32x4 dacc[2][4];
    #pragma unroll
    for(int rt=0;rt<2;++rt)
      #pragma unroll
      for(int ft=0;ft<4;++ft) dacc[rt][ft]=zero;
    #pragma unroll
    for(int rt=0;rt<2;++rt)
      #pragma unroll
      for(int ft=0;ft<4;++ft)
        #pragma unroll
        for(int ks=0;ks<2;++ks){
          dacc[rt][ft]=mfma16(ka_h[rt][ks],pb[ft][ks],dacc[rt][ft]);
          dacc[rt][ft]=mfma16(ka_l[rt][ks],pb[ft][ks],dacc[rt][ft]);
        }
    float dg[2][4];
    #pragma unroll
    for(int rt=0;rt<2;++rt)
      #pragma unroll
      for(int r=0;r<4;++r) dg[rt][r]=__shfl(dsq[rt],4*g+r);
    // kp = RATIO*exp(dd - diag - stab) + REPS, rounded to bf16;
    // ksum accumulates the SAME rounded value (consistent features).
    #pragma unroll
    for(int rt=0;rt<2;++rt)
      #pragma unroll
      for(int ft=0;ft<4;++ft){
        int f=fb+16*ft+l15;
        #pragma unroll
        for(int r=0;r<4;++r){
          float kp=fmaf(RATIO,__expf(dacc[rt][ft][r]-dg[rt][r]-stab),REPS);
          bf16 hb=(bf16)kp;
          ksacc[ft]+=(float)hb;
          int nn=16*rt+4*g+r;
          kpt_h[f*40+nn]=hb;
        }
      }
    // V b-frags (split from prefetched registers)
    bf16x8 vb_h[4], vb_l[4];
    #pragma unroll
    for(int et=0;et<4;++et) split8(vx[et],vb_h[et],vb_l[et]);
    // ctx += kp_b^T @ V (kp single-plane x V split = 2-pass)
    #pragma unroll
    for(int mt=0;mt<4;++mt){
      bf16x8 a_h=*(const bf16x8*)&kpt_h[(fb+16*mt+l15)*40+8*g];
      #pragma unroll
      for(int et=0;et<4;++et){
        cacc[mt][et]=mfma16(a_h,vb_h[et],cacc[mt][et]);
        cacc[mt][et]=mfma16(a_h,vb_l[et],cacc[mt][et]);
      }
    }
    __syncthreads();   // kstage[cur] reads done; staging vmcnt drained
    cur^=1;
  }
  // ---- ksum cross-g reduce (both modes) ----
  float ksred[4];
  #pragma unroll
  for(int ft=0;ft<4;++ft){
    float s=ksacc[ft];
    s+=__shfl_xor(s,16); s+=__shfl_xor(s,32);
    ksred[ft]=s;
  }
  if(mode){
    float* cg=part+((long)ch*BH_+bh)*SLICE_W;
    #pragma unroll
    for(int mt=0;mt<4;++mt)
      #pragma unroll
      for(int et=0;et<4;++et)
        #pragma unroll
        for(int r=0;r<4;++r)
          cg[(fb+16*mt+4*g+r)*64+16*et+l15]=cacc[mt][et][r];
    if(g==0){
      #pragma unroll
      for(int ft=0;ft<4;++ft)
        cg[16384+fb+16*ft+l15]=ksred[ft];
    }
  }else{
    float* cg=ctx_g+(long)bh*16384;
    #pragma unroll
    for(int mt=0;mt<4;++mt)
      #pragma unroll
      for(int et=0;et<4;++et)
        #pragma unroll
        for(int r=0;r<4;++r)
          atomicAdd(&cg[(fb+16*mt+4*g+r)*64+16*et+l15],cacc[mt][et][r]);
    if(g==0){
      #pragma unroll
      for(int ft=0;ft<4;++ft)
        atomicAdd(&ksum_g[bh*256+fb+16*ft+l15],ksred[ft]);
    }
  }
}

// sum the 32 partial slices -> ctx / ksum. grid 520 x 256.
__global__ void __launch_bounds__(256) redK(const float* __restrict__ part,
    float* __restrict__ ctx_g, float* __restrict__ ksum_g){
  long t=(long)blockIdx.x*256+threadIdx.x;
  const long TOT=(long)BH_*SLICE_W;          // 266240
  for(long o=t;o<TOT;o+=(long)gridDim.x*256){
    int bh=(int)(o/SLICE_W), idx=(int)(o%SLICE_W);
    float s=0.f;
    #pragma unroll 8
    for(int ch=0;ch<32;++ch)
      s+=part[((long)ch*BH_+bh)*SLICE_W+idx];
    if(idx<16384) ctx_g[(long)bh*16384+idx]=s;
    else          ksum_g[bh*256+idx-16384]=s;
  }
}

// fused qp + out. grid = 512: 16 bh * 32 chunks of 256 rows, 4 FAT iters of
// 64 rows. Q LDS-staged dbuf (16KB tiles); dd per row-tile (qa transient);
// qp single-bf16 ds_write_b16; epilogue uses v_rcp_f32.
__global__ void __launch_bounds__(256,2) qoK(const float* __restrict__ Qg,
    const float* __restrict__ Pg, const float* __restrict__ ctx_g,
    const float* __restrict__ ksum_g, float* __restrict__ outg){
  __shared__ float qstage[2][4096];          // 2 x 16KB staged Q tiles (swizzled)
  __shared__ __align__(16) bf16 qpt[64*264]; // bf16 qp plane, [n][f], stride 264
  __shared__ float rmaxl[4][64];
  __shared__ float denl[4][64];
  int tid=threadIdx.x, w=tid>>6, lane=tid&63, l15=lane&15, g=lane>>4;
  int fb=w*64;
  int bh=blockIdx.x>>5, ch=blockIdx.x&31;
  long rowbase=(long)bh*N_ + ch*256;

  bf16x8 pb[4][2];
  load_P_frags1(Pg,fb,l15,g,pb);
  float ksv[4];
  #pragma unroll
  for(int ft=0;ft<4;++ft) ksv[ft]=ksum_g[bh*256+fb+16*ft+l15];
  // ctx b-frags for this wave's e-tile (et = w), split
  bf16x8 cb_h[8], cb_l[8];
  #pragma unroll
  for(int ks=0;ks<8;++ks){
    float x[8];
    #pragma unroll
    for(int j=0;j<8;++j) x[j]=ctx_g[(long)bh*16384+(32*ks+8*g+j)*64+16*w+l15];
    split8(x,cb_h[ks],cb_l[ks]);
  }
  f32x4 zero={0.f,0.f,0.f,0.f};
  int cur=0;
  STAGE64(Qg, &qstage[0][0], rowbase);
  __syncthreads();                     // drain staging for iter 0
  #pragma unroll 1
  for(int it=0;it<4;++it){
    long n0=rowbase+it*64;
    long np=(it==3)? rowbase : n0+64;  // last iter: dummy re-stage (harmless)
    STAGE64(Qg, &qstage[cur^1][0], np);// issue next tile; lands by next barrier
    // dd per row-tile rt (qa transient -> low register pressure)
    f32x4 dacc[4][4];
    float dsq[4];
    #pragma unroll
    for(int rt=0;rt<4;++rt){
      bf16x8 qa_h[2], qa_l[2];
      float ss=0.f;
      #pragma unroll
      for(int ks=0;ks<2;++ks){
        float x[8]; FRAGREAD(x,&qstage[cur][0],16*rt+l15,ks);
        #pragma unroll
        for(int i=0;i<8;++i) ss=fmaf(x[i],x[i],ss);
        split8(x,qa_h[ks],qa_l[ks]);
      }
      ss+=__shfl_xor(ss,16); ss+=__shfl_xor(ss,32);
      dsq[rt]=DSC*ss;
      #pragma unroll
      for(int ft=0;ft<4;++ft) dacc[rt][ft]=zero;
      #pragma unroll
      for(int ft=0;ft<4;++ft)
        #pragma unroll
        for(int ks=0;ks<2;++ks){
          dacc[rt][ft]=mfma16(qa_h[ks],pb[ft][ks],dacc[rt][ft]);
          dacc[rt][ft]=mfma16(qa_l[ks],pb[ft][ks],dacc[rt][ft]);
        }
    }
    float dg[4][4];
    #pragma unroll
    for(int rt=0;rt<4;++rt)
      #pragma unroll
      for(int r=0;r<4;++r) dg[rt][r]=__shfl(dsq[rt],4*g+r);
    // per-wave rowmax over its f-strip
    #pragma unroll
    for(int rt=0;rt<4;++rt)
      #pragma unroll
      for(int r=0;r<4;++r){
        float m=fmaxf(fmaxf(dacc[rt][0][r],dacc[rt][1][r]),
                      fmaxf(dacc[rt][2][r],dacc[rt][3][r]));
        m=fmaxf(m,__shfl_xor(m,1)); m=fmaxf(m,__shfl_xor(m,2));
        m=fmaxf(m,__shfl_xor(m,4)); m=fmaxf(m,__shfl_xor(m,8));
        if(l15==0) rmaxl[w][16*rt+4*g+r]=m;
      }
    __syncthreads();   // rowmax planes ready (also fences staging of cur^1)
    // qp (rounded bf16), den partials from the SAME rounded value,
    // direct b16 writes into qpt[n][f]
    #pragma unroll
    for(int rt=0;rt<4;++rt)
      #pragma unroll
      for(int r=0;r<4;++r){
        int nn=16*rt+4*g+r;
        float rm=fmaxf(fmaxf(rmaxl[0][nn],rmaxl[1][nn]),
                       fmaxf(rmaxl[2][nn],rmaxl[3][nn]));
        float dp=0.f;
        #pragma unroll
        for(int ft=0;ft<4;++ft){
          float qp=fmaf(RATIO,__expf(dacc[rt][ft][r]-dg[rt][r]-rm),REPS);
          bf16 hb=(bf16)qp;
          dp=fmaf((float)hb,ksv[ft],dp);
          qpt[nn*264 + fb+16*ft+l15]=hb;
        }
        dp+=__shfl_xor(dp,1); dp+=__shfl_xor(dp,2);
        dp+=__shfl_xor(dp,4); dp+=__shfl_xor(dp,8);
        if(l15==0) denl[w][nn]=dp;
      }
    __syncthreads();   // qpt + denl ready
    // out = qp_b @ ctx (single-plane qp x split ctx = 2-pass)
    f32x4 oacc[4];
    #pragma unroll
    for(int mt=0;mt<4;++mt) oacc[mt]=zero;
    #pragma unroll
    for(int ks=0;ks<8;++ks)
      #pragma unroll
      for(int mt=0;mt<4;++mt){
        bf16x8 a_h=*(const bf16x8*)&qpt[(16*mt+l15)*264+32*ks+8*g];
        oacc[mt]=mfma16(a_h,cb_h[ks],oacc[mt]);
        oacc[mt]=mfma16(a_h,cb_l[ks],oacc[mt]);
      }
    #pragma unroll
    for(int mt=0;mt<4;++mt)
      #pragma unroll
      for(int r=0;r<4;++r){
        int nn=16*mt+4*g+r;
        float den=denl[0][nn]+denl[1][nn]+denl[2][nn]+denl[3][nn];
        float rden=__builtin_amdgcn_rcpf(den);
        outg[(n0+nn)*64+16*w+l15]=oacc[mt][r]*rden;
      }
    cur^=1;
  }
}

// ---------------- host ----------------

extern "C" void kernel_launch(void* const* d_in, const int* in_sizes, int n_in,
                              void* d_out, int out_size, void* d_ws, size_t ws_size,
                              hipStream_t stream) {
  (void)in_sizes; (void)n_in; (void)out_size;
  const float* q = (const float*)d_in[0];
  const float* k = (const float*)d_in[1];
  const float* v = (const float*)d_in[2];
  const float* P = (const float*)d_in[3];
  float* out = (float*)d_out;

  unsigned* stab = (unsigned*)d_ws;
  float* ctx  = (float*)d_ws + CTX_W;
  float* ksum = (float*)d_ws + KSUM_W;
  float* part = (float*)d_ws + PART_W;

  size_t need = ((size_t)PART_W + (size_t)32*BH_*SLICE_W) * 4;  // ~35.1 MB
  int mode = (ws_size >= need) ? 1 : 0;

  hipLaunchKernelGGL(initK, dim3(256), dim3(256), 0, stream, (unsigned*)d_ws);
  hipLaunchKernelGGL(stabK, dim3(512), dim3(256), 0, stream, k, P, stab);
  hipLaunchKernelGGL(ctxK, dim3(512), dim3(256), 0, stream, k, v, P, stab,
                     ctx, ksum, part, mode);
  if(mode)
    hipLaunchKernelGGL(redK, dim3(520), dim3(256), 0, stream, part, ctx, ksum);
  hipLaunchKernelGGL(qoK, dim3(512), dim3(256), 0, stream, q, P, ctx, ksum, out);
}

// Round 17
// 118.281 us; speedup vs baseline: 1.1048x; 1.1048x over previous
//
#include <hip/hip_runtime.h>

// Performer (FAVOR+) attention, MI355X, split-bf16 MFMA.
// B=2 H=8 N=8192 D=64 F=256; rows R = 131072.
// Round 17 = round 16 with the DPP ctrl as a TEMPLATE parameter (the
// builtin requires a constant-int immediate; function-arg failed to fold).
// qoK: rowmax/den butterflies via DPP (VALU pipe) instead of __shfl_xor
// (ds_swizzle, LDS pipe, ~60-120cy each in 4-deep chains x 32 rows/iter —
// the unaccounted ~40us of qoK stall). ctxK/stabK/redK unchanged (controls).

typedef __bf16 bf16;
typedef __bf16 bf16x8 __attribute__((ext_vector_type(8)));
typedef _Float16 f16;
typedef f16 f16x8 __attribute__((ext_vector_type(8)));
typedef float f32x4 __attribute__((ext_vector_type(4)));

#define N_    8192
#define BH_   16
#define NRM   0.35355339059327379f   // 64^-0.25
#define RATIO 0.0625f                // 256^-0.5
#define DSC   0.0625f                // 0.5*NRM^2
#define REPS  6.25e-6f               // RATIO*1e-4

#define CTX_W  16
#define KSUM_W (CTX_W + BH_*256*64)     // 262160
#define ZERO_W (KSUM_W + BH_*256)       // 266256
#define SLICE_W 16640                   // 16384 ctx + 256 ksum per (bh,ch)
#define PART_W  ZERO_W                  // partials start here (32*16*16640 w)

static __device__ __forceinline__ unsigned mapmax(float x){
  unsigned u=__float_as_uint(x); return (u&0x80000000u)? ~u : (u|0x80000000u);
}
static __device__ __forceinline__ float unmapmax(unsigned u){
  return __uint_as_float((u&0x80000000u)? (u&0x7fffffffu) : ~u);
}
static __device__ __forceinline__ f32x4 mfma16(bf16x8 a, bf16x8 b, f32x4 c){
  return __builtin_amdgcn_mfma_f32_16x16x32_bf16(a,b,c,0,0,0);
}
static __device__ __forceinline__ f32x4 mfma16h(f16x8 a, f16x8 b, f32x4 c){
  return __builtin_amdgcn_mfma_f32_16x16x32_f16(a,b,c,0,0,0);
}
// DPP lane permute within aligned 16-lane rows (VALU pipe, no LDS).
// ctrl must be an immediate -> template parameter.
template<int CTRL>
static __device__ __forceinline__ float dppf(float x){
  int v=__builtin_amdgcn_update_dpp(0, __float_as_int(x), CTRL, 0xF, 0xF, true);
  return __int_as_float(v);
}
// 16-lane-row max/sum butterflies: xor1, xor2, ^7(half-mirror), ^15(mirror)
static __device__ __forceinline__ float max16_dpp(float x){
  x=fmaxf(x,dppf<0xB1>(x));  // quad_perm [1,0,3,2]
  x=fmaxf(x,dppf<0x4E>(x));  // quad_perm [2,3,0,1]
  x=fmaxf(x,dppf<0x141>(x)); // row_half_mirror
  x=fmaxf(x,dppf<0x140>(x)); // row_mirror
  return x;
}
static __device__ __forceinline__ float sum16_dpp(float x){
  x+=dppf<0xB1>(x);
  x+=dppf<0x4E>(x);
  x+=dppf<0x141>(x);
  x+=dppf<0x140>(x);
  return x;
}
static __device__ __forceinline__ void ld8(const float* __restrict__ p, float* x){
  float4 a=*(const float4*)p; float4 b=*(const float4*)(p+4);
  x[0]=a.x; x[1]=a.y; x[2]=a.z; x[3]=a.w; x[4]=b.x; x[5]=b.y; x[6]=b.z; x[7]=b.w;
}
static __device__ __forceinline__ void split8(const float* x, bf16x8& h, bf16x8& l){
  #pragma unroll
  for(int i=0;i<8;++i){ bf16 hi=(bf16)x[i]; h[i]=hi; l[i]=(bf16)(x[i]-(float)hi); }
}
static __device__ __forceinline__ void cvt8b(const float* x, bf16x8& h){
  #pragma unroll
  for(int i=0;i<8;++i) h[i]=(bf16)x[i];
}
static __device__ __forceinline__ void cvt8h(const float* x, f16x8& h){
  #pragma unroll
  for(int i=0;i<8;++i) h[i]=(f16)x[i];
}
static __device__ __forceinline__ void gload16(const float* g, float* l){
  __builtin_amdgcn_global_load_lds(
      (const __attribute__((address_space(1))) unsigned*)g,
      (__attribute__((address_space(3))) unsigned*)l, 16, 0, 0);
}
// P-hat (NRM*P) b-fragments, SINGLE bf16 plane: [ft 0..3][ks 0..1]
static __device__ __forceinline__ void load_P_frags1(const float* __restrict__ Pg,
    int fb, int l15, int g, bf16x8 (&pb)[4][2]){
  #pragma unroll
  for(int ft=0;ft<4;++ft)
    #pragma unroll
    for(int ks=0;ks<2;++ks){
      float x[8]; ld8(&Pg[(fb+16*ft+l15)*64+32*ks+8*g],x);
      #pragma unroll
      for(int i=0;i<8;++i) x[i]*=NRM;
      cvt8b(x,pb[ft][ks]);
    }
}

// stage 32 rows x 64 floats from Xg into LDS buf, source XOR-swizzled by
// row&15 so fragment-pattern b128 reads are conflict-free (r9 pattern).
#define STAGE32(Xg, bufptr, n0s) do{                                      \
    int u0_=tid, u1_=tid+256;                                             \
    int r0_=u0_>>4, c0_=u0_&15, r1_=u1_>>4, c1_=u1_&15;                   \
    gload16((Xg)+((n0s)+r0_)*64+((c0_^(r0_&15))<<2), (bufptr)+u0_*4);     \
    gload16((Xg)+((n0s)+r1_)*64+((c1_^(r1_&15))<<2), (bufptr)+u1_*4);     \
  }while(0)
// stage 64 rows x 64 floats (qoK fat iters)
#define STAGE64(Xg, bufptr, n0s) do{                                      \
    _Pragma("unroll")                                                     \
    for(int ii_=0;ii_<4;++ii_){                                           \
      int u_=tid+256*ii_;                                                 \
      int r_=u_>>4, c_=u_&15;                                             \
      gload16((Xg)+((n0s)+r_)*64+((c_^(r_&15))<<2), (bufptr)+u_*4);       \
    }                                                                     \
  }while(0)
// x[8] <- staged row rr, k-chunk ks (two swizzled b128 reads)
#define FRAGREAD(xv, bufptr, rr, ksv) do{                                 \
    int cc0_=(8*(ksv)+2*g)^((rr)&15);                                     \
    int cc1_=cc0_^1;                                                      \
    float4 a_=*(const float4*)((bufptr)+(rr)*64+cc0_*4);                  \
    float4 b_=*(const float4*)((bufptr)+(rr)*64+cc1_*4);                  \
    xv[0]=a_.x; xv[1]=a_.y; xv[2]=a_.z; xv[3]=a_.w;                       \
    xv[4]=b_.x; xv[5]=b_.y; xv[6]=b_.z; xv[7]=b_.w;                       \
  }while(0)

// ---------------- kernels ----------------

__global__ void __launch_bounds__(256) initK(unsigned* ws){
  for(int i=blockIdx.x*256+threadIdx.x;i<ZERO_W;i+=gridDim.x*256) ws[i]=0u;
}

// global max of dd_k (single-f16). grid 512, 4 iters of 64 rows (P amortized).
__global__ void __launch_bounds__(256) stabK(const float* __restrict__ Kg,
                                             const float* __restrict__ Pg,
                                             unsigned* __restrict__ stab_ws){
  __shared__ float red[4];
  int tid=threadIdx.x, w=tid>>6, lane=tid&63, l15=lane&15, g=lane>>4;
  int fb=w*64;
  f16x8 pb[4][2];
  #pragma unroll
  for(int ft=0;ft<4;++ft)
    #pragma unroll
    for(int ks=0;ks<2;++ks){
      float x[8]; ld8(&Pg[(fb+16*ft+l15)*64+32*ks+8*g],x);
      #pragma unroll
      for(int i=0;i<8;++i) x[i]*=NRM;
      cvt8h(x,pb[ft][ks]);
    }
  float m=-3.4e38f;
  long base=(long)blockIdx.x*256;
  f32x4 zero={0.f,0.f,0.f,0.f};
  #pragma unroll 1
  for(int it=0;it<4;++it){
    long row0=base+it*64;
    f16x8 ka[4][2];
    #pragma unroll
    for(int rt=0;rt<4;++rt)
      #pragma unroll
      for(int ks=0;ks<2;++ks){
        float x[8]; ld8(&Kg[(row0+16*rt+l15)*64+32*ks+8*g],x);
        cvt8h(x,ka[rt][ks]);
      }
    f32x4 acc[4][4];
    #pragma unroll
    for(int rt=0;rt<4;++rt)
      #pragma unroll
      for(int ft=0;ft<4;++ft) acc[rt][ft]=zero;
    #pragma unroll
    for(int rt=0;rt<4;++rt)
      #pragma unroll
      for(int ft=0;ft<4;++ft)
        #pragma unroll
        for(int ks=0;ks<2;++ks)
          acc[rt][ft]=mfma16h(ka[rt][ks],pb[ft][ks],acc[rt][ft]);
    #pragma unroll
    for(int rt=0;rt<4;++rt)
      #pragma unroll
      for(int ft=0;ft<4;++ft)
        #pragma unroll
        for(int r=0;r<4;++r) m=fmaxf(m,acc[rt][ft][r]);
  }
  #pragma unroll
  for(int off=1;off<64;off<<=1) m=fmaxf(m,__shfl_xor(m,off));
  if(lane==0) red[w]=m;
  __syncthreads();
  if(tid==0){
    m=fmaxf(fmaxf(red[0],red[1]),fmaxf(red[2],red[3]));
    atomicMax(stab_ws,mapmax(m));
  }
}

// kp + ctx/ksum accumulation. grid = 512: 16 bh * 32 chunks of 256 rows,
// 8 iters. K LDS-staged dbuf; V reg-prefetched; P single bf16; 2-pass dd.
// Epilogue: mode=1 -> plain stores into private partial slice (bh,ch);
// mode=0 -> atomic path. UNCHANGED from round 14.
__global__ void __launch_bounds__(256,2) ctxK(const float* __restrict__ Kg,
    const float* __restrict__ Vg, const float* __restrict__ Pg,
    const unsigned* __restrict__ stab_ws, float* __restrict__ ctx_g,
    float* __restrict__ ksum_g, float* __restrict__ part, int mode){
  __shared__ __align__(16) bf16 kpt_h[256*40];   // 20KB
  __shared__ float kstage[2][2048];              // 2 x 8KB staged K tiles
  int tid=threadIdx.x, w=tid>>6, lane=tid&63, l15=lane&15, g=lane>>4;
  int fb=w*64;
  int bh=blockIdx.x>>5, ch=blockIdx.x&31;
  long rowbase=(long)bh*N_ + ch*256;
  float stab=unmapmax(*stab_ws);
  bf16x8 pb[4][2];
  load_P_frags1(Pg,fb,l15,g,pb);
  f32x4 zero={0.f,0.f,0.f,0.f};
  f32x4 cacc[4][4];
  #pragma unroll
  for(int mt=0;mt<4;++mt)
    #pragma unroll
    for(int et=0;et<4;++et) cacc[mt][et]=zero;
  float ksacc[4]={0.f,0.f,0.f,0.f};
  int cur=0;
  STAGE32(Kg, &kstage[0][0], rowbase);
  __syncthreads();                       // drain staging for iter 0
  #pragma unroll 1
  for(int it=0;it<8;++it){
    long n0=rowbase+it*32;
    long np=(it==7)? rowbase : n0+32;    // last iter: dummy re-stage (harmless)
    STAGE32(Kg, &kstage[cur^1][0], np);  // issue next K tile; lands by barrier
    // V raw prefetch (latency hidden under dd-GEMM + exp)
    float vx[4][8];
    #pragma unroll
    for(int et=0;et<4;++et)
      #pragma unroll
      for(int j=0;j<8;++j) vx[et][j]=Vg[(n0+8*g+j)*64+16*et+l15];
    // K a-frags (split) + row sums of squares, from staged LDS
    bf16x8 ka_h[2][2], ka_l[2][2];
    float dsq[2];
    #pragma unroll
    for(int rt=0;rt<2;++rt){
      float ss=0.f;
      #pragma unroll
      for(int ks=0;ks<2;++ks){
        float x[8]; FRAGREAD(x,&kstage[cur][0],16*rt+l15,ks);
        #pragma unroll
        for(int i=0;i<8;++i) ss=fmaf(x[i],x[i],ss);
        split8(x,ka_h[rt][ks],ka_l[rt][ks]);
      }
      ss+=__shfl_xor(ss,16); ss+=__shfl_xor(ss,32);
      dsq[rt]=DSC*ss;
    }
    // dd = (Kh + Kl) @ P (2-pass; P single bf16)
    f32x4 dacc[2][4];
    #pragma unroll
    for(int rt=0;rt<2;++rt)
      #pragma unroll
      for(int ft=0;ft<4;++ft) dacc[rt][ft]=zero;
    #pragma unroll
    for(int rt=0;rt<2;++rt)
      #pragma unroll
      for(int ft=0;ft<4;++ft)
        #pragma unroll
        for(int ks=0;ks<2;++ks){
          dacc[rt][ft]=mfma16(ka_h[rt][ks],pb[ft][ks],dacc[rt][ft]);
          dacc[rt][ft]=mfma16(ka_l[rt][ks],pb[ft][ks],dacc[rt][ft]);
        }
    float dg[2][4];
    #pragma unroll
    for(int rt=0;rt<2;++rt)
      #pragma unroll
      for(int r=0;r<4;++r) dg[rt][r]=__shfl(dsq[rt],4*g+r);
    // kp = RATIO*exp(dd - diag - stab) + REPS, rounded to bf16;
    // ksum accumulates the SAME rounded value (consistent features).
    #pragma unroll
    for(int rt=0;rt<2;++rt)
      #pragma unroll
      for(int ft=0;ft<4;++ft){
        int f=fb+16*ft+l15;
        #pragma unroll
        for(int r=0;r<4;++r){
          float kp=fmaf(RATIO,__expf(dacc[rt][ft][r]-dg[rt][r]-stab),REPS);
          bf16 hb=(bf16)kp;
          ksacc[ft]+=(float)hb;
          int nn=16*rt+4*g+r;
          kpt_h[f*40+nn]=hb;
        }
      }
    // V b-frags (split from prefetched registers)
    bf16x8 vb_h[4], vb_l[4];
    #pragma unroll
    for(int et=0;et<4;++et) split8(vx[et],vb_h[et],vb_l[et]);
    // ctx += kp_b^T @ V (kp single-plane x V split = 2-pass)
    #pragma unroll
    for(int mt=0;mt<4;++mt){
      bf16x8 a_h=*(const bf16x8*)&kpt_h[(fb+16*mt+l15)*40+8*g];
      #pragma unroll
      for(int et=0;et<4;++et){
        cacc[mt][et]=mfma16(a_h,vb_h[et],cacc[mt][et]);
        cacc[mt][et]=mfma16(a_h,vb_l[et],cacc[mt][et]);
      }
    }
    __syncthreads();   // kstage[cur] reads done; staging vmcnt drained
    cur^=1;
  }
  // ---- ksum cross-g reduce (both modes) ----
  float ksred[4];
  #pragma unroll
  for(int ft=0;ft<4;++ft){
    float s=ksacc[ft];
    s+=__shfl_xor(s,16); s+=__shfl_xor(s,32);
    ksred[ft]=s;
  }
  if(mode){
    float* cg=part+((long)ch*BH_+bh)*SLICE_W;
    #pragma unroll
    for(int mt=0;mt<4;++mt)
      #pragma unroll
      for(int et=0;et<4;++et)
        #pragma unroll
        for(int r=0;r<4;++r)
          cg[(fb+16*mt+4*g+r)*64+16*et+l15]=cacc[mt][et][r];
    if(g==0){
      #pragma unroll
      for(int ft=0;ft<4;++ft)
        cg[16384+fb+16*ft+l15]=ksred[ft];
    }
  }else{
    float* cg=ctx_g+(long)bh*16384;
    #pragma unroll
    for(int mt=0;mt<4;++mt)
      #pragma unroll
      for(int et=0;et<4;++et)
        #pragma unroll
        for(int r=0;r<4;++r)
          atomicAdd(&cg[(fb+16*mt+4*g+r)*64+16*et+l15],cacc[mt][et][r]);
    if(g==0){
      #pragma unroll
      for(int ft=0;ft<4;++ft)
        atomicAdd(&ksum_g[bh*256+fb+16*ft+l15],ksred[ft]);
    }
  }
}

// sum the 32 partial slices -> ctx / ksum. grid 520 x 256.
__global__ void __launch_bounds__(256) redK(const float* __restrict__ part,
    float* __restrict__ ctx_g, float* __restrict__ ksum_g){
  long t=(long)blockIdx.x*256+threadIdx.x;
  const long TOT=(long)BH_*SLICE_W;          // 266240
  for(long o=t;o<TOT;o+=(long)gridDim.x*256){
    int bh=(int)(o/SLICE_W), idx=(int)(o%SLICE_W);
    float s=0.f;
    #pragma unroll 8
    for(int ch=0;ch<32;++ch)
      s+=part[((long)ch*BH_+bh)*SLICE_W+idx];
    if(idx<16384) ctx_g[(long)bh*16384+idx]=s;
    else          ksum_g[bh*256+idx-16384]=s;
  }
}

// fused qp + out. grid = 512: 16 bh * 32 chunks of 256 rows, 4 fat iters of
// 64 rows. Q LDS-staged dbuf; rowmax/den reduces via DPP butterflies
// (VALU pipe) instead of __shfl_xor (LDS pipe). qp single-bf16 ds_write_b16.
__global__ void __launch_bounds__(256,2) qoK(const float* __restrict__ Qg,
    const float* __restrict__ Pg, const float* __restrict__ ctx_g,
    const float* __restrict__ ksum_g, float* __restrict__ outg){
  __shared__ float qstage[2][4096];          // 2 x 16KB staged Q tiles (swizzled)
  __shared__ __align__(16) bf16 qpt[64*264]; // bf16 qp plane, [n][f], stride 264
  __shared__ float rmaxl[4][64];
  __shared__ float denl[4][64];
  int tid=threadIdx.x, w=tid>>6, lane=tid&63, l15=lane&15, g=lane>>4;
  int fb=w*64;
  int bh=blockIdx.x>>5, ch=blockIdx.x&31;
  long rowbase=(long)bh*N_ + ch*256;

  bf16x8 pb[4][2];
  load_P_frags1(Pg,fb,l15,g,pb);
  float ksv[4];
  #pragma unroll
  for(int ft=0;ft<4;++ft) ksv[ft]=ksum_g[bh*256+fb+16*ft+l15];
  // ctx b-frags for this wave's e-tile (et = w), split
  bf16x8 cb_h[8], cb_l[8];
  #pragma unroll
  for(int ks=0;ks<8;++ks){
    float x[8];
    #pragma unroll
    for(int j=0;j<8;++j) x[j]=ctx_g[(long)bh*16384+(32*ks+8*g+j)*64+16*w+l15];
    split8(x,cb_h[ks],cb_l[ks]);
  }
  f32x4 zero={0.f,0.f,0.f,0.f};
  int cur=0;
  STAGE64(Qg, &qstage[0][0], rowbase);
  __syncthreads();                     // drain staging for iter 0
  #pragma unroll 1
  for(int it=0;it<4;++it){
    long n0=rowbase+it*64;
    long np=(it==3)? rowbase : n0+64;  // last iter: dummy re-stage (harmless)
    STAGE64(Qg, &qstage[cur^1][0], np);// issue next tile; lands by next barrier
    // dd per row-tile rt (qa transient -> low register pressure)
    f32x4 dacc[4][4];
    float dsq[4];
    #pragma unroll
    for(int rt=0;rt<4;++rt){
      bf16x8 qa_h[2], qa_l[2];
      float ss=0.f;
      #pragma unroll
      for(int ks=0;ks<2;++ks){
        float x[8]; FRAGREAD(x,&qstage[cur][0],16*rt+l15,ks);
        #pragma unroll
        for(int i=0;i<8;++i) ss=fmaf(x[i],x[i],ss);
        split8(x,qa_h[ks],qa_l[ks]);
      }
      ss+=__shfl_xor(ss,16); ss+=__shfl_xor(ss,32);
      dsq[rt]=DSC*ss;
      #pragma unroll
      for(int ft=0;ft<4;++ft) dacc[rt][ft]=zero;
      #pragma unroll
      for(int ft=0;ft<4;++ft)
        #pragma unroll
        for(int ks=0;ks<2;++ks){
          dacc[rt][ft]=mfma16(qa_h[ks],pb[ft][ks],dacc[rt][ft]);
          dacc[rt][ft]=mfma16(qa_l[ks],pb[ft][ks],dacc[rt][ft]);
        }
    }
    float dg[4][4];
    #pragma unroll
    for(int rt=0;rt<4;++rt)
      #pragma unroll
      for(int r=0;r<4;++r) dg[rt][r]=__shfl(dsq[rt],4*g+r);
    // per-wave rowmax over its f-strip (DPP butterfly, VALU pipe)
    #pragma unroll
    for(int rt=0;rt<4;++rt)
      #pragma unroll
      for(int r=0;r<4;++r){
        float m=fmaxf(fmaxf(dacc[rt][0][r],dacc[rt][1][r]),
                      fmaxf(dacc[rt][2][r],dacc[rt][3][r]));
        m=max16_dpp(m);
        if(l15==0) rmaxl[w][16*rt+4*g+r]=m;
      }
    __syncthreads();   // rowmax planes ready (also fences staging of cur^1)
    // qp (rounded bf16), den partials from the SAME rounded value,
    // direct b16 writes into qpt[n][f]; den reduce via DPP butterfly
    #pragma unroll
    for(int rt=0;rt<4;++rt)
      #pragma unroll
      for(int r=0;r<4;++r){
        int nn=16*rt+4*g+r;
        float rm=fmaxf(fmaxf(rmaxl[0][nn],rmaxl[1][nn]),
                       fmaxf(rmaxl[2][nn],rmaxl[3][nn]));
        float dp=0.f;
        #pragma unroll
        for(int ft=0;ft<4;++ft){
          float qp=fmaf(RATIO,__expf(dacc[rt][ft][r]-dg[rt][r]-rm),REPS);
          bf16 hb=(bf16)qp;
          dp=fmaf((float)hb,ksv[ft],dp);
          qpt[nn*264 + fb+16*ft+l15]=hb;
        }
        dp=sum16_dpp(dp);
        if(l15==0) denl[w][nn]=dp;
      }
    __syncthreads();   // qpt + denl ready
    // out = qp_b @ ctx (single-plane qp x split ctx = 2-pass)
    f32x4 oacc[4];
    #pragma unroll
    for(int mt=0;mt<4;++mt) oacc[mt]=zero;
    #pragma unroll
    for(int ks=0;ks<8;++ks)
      #pragma unroll
      for(int mt=0;mt<4;++mt){
        bf16x8 a_h=*(const bf16x8*)&qpt[(16*mt+l15)*264+32*ks+8*g];
        oacc[mt]=mfma16(a_h,cb_h[ks],oacc[mt]);
        oacc[mt]=mfma16(a_h,cb_l[ks],oacc[mt]);
      }
    #pragma unroll
    for(int mt=0;mt<4;++mt)
      #pragma unroll
      for(int r=0;r<4;++r){
        int nn=16*mt+4*g+r;
        float den=denl[0][nn]+denl[1][nn]+denl[2][nn]+denl[3][nn];
        float rden=__builtin_amdgcn_rcpf(den);
        outg[(n0+nn)*64+16*w+l15]=oacc[mt][r]*rden;
      }
    cur^=1;
  }
}

// ---------------- host ----------------

extern "C" void kernel_launch(void* const* d_in, const int* in_sizes, int n_in,
                              void* d_out, int out_size, void* d_ws, size_t ws_size,
                              hipStream_t stream) {
  (void)in_sizes; (void)n_in; (void)out_size;
  const float* q = (const float*)d_in[0];
  const float* k = (const float*)d_in[1];
  const float* v = (const float*)d_in[2];
  const float* P = (const float*)d_in[3];
  float* out = (float*)d_out;

  unsigned* stab = (unsigned*)d_ws;
  float* ctx  = (float*)d_ws + CTX_W;
  float* ksum = (float*)d_ws + KSUM_W;
  float* part = (float*)d_ws + PART_W;

  size_t need = ((size_t)PART_W + (size_t)32*BH_*SLICE_W) * 4;  // ~35.1 MB
  int mode = (ws_size >= need) ? 1 : 0;

  hipLaunchKernelGGL(initK, dim3(256), dim3(256), 0, stream, (unsigned*)d_ws);
  hipLaunchKernelGGL(stabK, dim3(512), dim3(256), 0, stream, k, P, stab);
  hipLaunchKernelGGL(ctxK, dim3(512), dim3(256), 0, stream, k, v, P, stab,
                     ctx, ksum, part, mode);
  if(mode)
    hipLaunchKernelGGL(redK, dim3(520), dim3(256), 0, stream, part, ctx, ksum);
  hipLaunchKernelGGL(qoK, dim3(512), dim3(256), 0, stream, q, P, ctx, ksum, out);
}

// Round 18
// 111.106 us; speedup vs baseline: 1.1762x; 1.0646x over previous
//
#include <hip/hip_runtime.h>

// Performer (FAVOR+) attention, MI355X, split-bf16 MFMA.
// B=2 H=8 N=8192 D=64 F=256; rows R = 131072.
// Round 18: (a) Q (qoK) and K (ctxK) rounded to SINGLE bf16 in the dd
// GEMMs (P already single since r12, which was bit-identical — consistent
// feature rounding cancels in num/den). dd 2-pass -> 1-pass: -32 MFMA/iter
// qoK, -16/iter ctxK, half the split8 VALU. V/ctx stay split (their error
// hits out directly). (b) T5 s_setprio(1) around MFMA clusters in both.
// r17 established: shfl_xor = LDS-pipe ~60-120cy; qoK butterflies are DPP.

typedef __bf16 bf16;
typedef __bf16 bf16x8 __attribute__((ext_vector_type(8)));
typedef _Float16 f16;
typedef f16 f16x8 __attribute__((ext_vector_type(8)));
typedef float f32x4 __attribute__((ext_vector_type(4)));

#define N_    8192
#define BH_   16
#define NRM   0.35355339059327379f   // 64^-0.25
#define RATIO 0.0625f                // 256^-0.5
#define DSC   0.0625f                // 0.5*NRM^2
#define REPS  6.25e-6f               // RATIO*1e-4

#define CTX_W  16
#define KSUM_W (CTX_W + BH_*256*64)     // 262160
#define ZERO_W (KSUM_W + BH_*256)       // 266256
#define SLICE_W 16640                   // 16384 ctx + 256 ksum per (bh,ch)
#define PART_W  ZERO_W                  // partials start here (32*16*16640 w)

static __device__ __forceinline__ unsigned mapmax(float x){
  unsigned u=__float_as_uint(x); return (u&0x80000000u)? ~u : (u|0x80000000u);
}
static __device__ __forceinline__ float unmapmax(unsigned u){
  return __uint_as_float((u&0x80000000u)? (u&0x7fffffffu) : ~u);
}
static __device__ __forceinline__ f32x4 mfma16(bf16x8 a, bf16x8 b, f32x4 c){
  return __builtin_amdgcn_mfma_f32_16x16x32_bf16(a,b,c,0,0,0);
}
static __device__ __forceinline__ f32x4 mfma16h(f16x8 a, f16x8 b, f32x4 c){
  return __builtin_amdgcn_mfma_f32_16x16x32_f16(a,b,c,0,0,0);
}
// DPP lane permute within aligned 16-lane rows (VALU pipe, no LDS).
template<int CTRL>
static __device__ __forceinline__ float dppf(float x){
  int v=__builtin_amdgcn_update_dpp(0, __float_as_int(x), CTRL, 0xF, 0xF, true);
  return __int_as_float(v);
}
static __device__ __forceinline__ float max16_dpp(float x){
  x=fmaxf(x,dppf<0xB1>(x));  // quad_perm [1,0,3,2]
  x=fmaxf(x,dppf<0x4E>(x));  // quad_perm [2,3,0,1]
  x=fmaxf(x,dppf<0x141>(x)); // row_half_mirror
  x=fmaxf(x,dppf<0x140>(x)); // row_mirror
  return x;
}
static __device__ __forceinline__ float sum16_dpp(float x){
  x+=dppf<0xB1>(x);
  x+=dppf<0x4E>(x);
  x+=dppf<0x141>(x);
  x+=dppf<0x140>(x);
  return x;
}
static __device__ __forceinline__ void ld8(const float* __restrict__ p, float* x){
  float4 a=*(const float4*)p; float4 b=*(const float4*)(p+4);
  x[0]=a.x; x[1]=a.y; x[2]=a.z; x[3]=a.w; x[4]=b.x; x[5]=b.y; x[6]=b.z; x[7]=b.w;
}
static __device__ __forceinline__ void split8(const float* x, bf16x8& h, bf16x8& l){
  #pragma unroll
  for(int i=0;i<8;++i){ bf16 hi=(bf16)x[i]; h[i]=hi; l[i]=(bf16)(x[i]-(float)hi); }
}
static __device__ __forceinline__ void cvt8b(const float* x, bf16x8& h){
  #pragma unroll
  for(int i=0;i<8;++i) h[i]=(bf16)x[i];
}
static __device__ __forceinline__ void cvt8h(const float* x, f16x8& h){
  #pragma unroll
  for(int i=0;i<8;++i) h[i]=(f16)x[i];
}
static __device__ __forceinline__ void gload16(const float* g, float* l){
  __builtin_amdgcn_global_load_lds(
      (const __attribute__((address_space(1))) unsigned*)g,
      (__attribute__((address_space(3))) unsigned*)l, 16, 0, 0);
}
// P-hat (NRM*P) b-fragments, SINGLE bf16 plane: [ft 0..3][ks 0..1]
static __device__ __forceinline__ void load_P_frags1(const float* __restrict__ Pg,
    int fb, int l15, int g, bf16x8 (&pb)[4][2]){
  #pragma unroll
  for(int ft=0;ft<4;++ft)
    #pragma unroll
    for(int ks=0;ks<2;++ks){
      float x[8]; ld8(&Pg[(fb+16*ft+l15)*64+32*ks+8*g],x);
      #pragma unroll
      for(int i=0;i<8;++i) x[i]*=NRM;
      cvt8b(x,pb[ft][ks]);
    }
}

// stage 32 rows x 64 floats from Xg into LDS buf, source XOR-swizzled by
// row&15 so fragment-pattern b128 reads are conflict-free (r9 pattern).
#define STAGE32(Xg, bufptr, n0s) do{                                      \
    int u0_=tid, u1_=tid+256;                                             \
    int r0_=u0_>>4, c0_=u0_&15, r1_=u1_>>4, c1_=u1_&15;                   \
    gload16((Xg)+((n0s)+r0_)*64+((c0_^(r0_&15))<<2), (bufptr)+u0_*4);     \
    gload16((Xg)+((n0s)+r1_)*64+((c1_^(r1_&15))<<2), (bufptr)+u1_*4);     \
  }while(0)
// stage 64 rows x 64 floats (qoK fat iters)
#define STAGE64(Xg, bufptr, n0s) do{                                      \
    _Pragma("unroll")                                                     \
    for(int ii_=0;ii_<4;++ii_){                                           \
      int u_=tid+256*ii_;                                                 \
      int r_=u_>>4, c_=u_&15;                                             \
      gload16((Xg)+((n0s)+r_)*64+((c_^(r_&15))<<2), (bufptr)+u_*4);       \
    }                                                                     \
  }while(0)
// x[8] <- staged row rr, k-chunk ks (two swizzled b128 reads)
#define FRAGREAD(xv, bufptr, rr, ksv) do{                                 \
    int cc0_=(8*(ksv)+2*g)^((rr)&15);                                     \
    int cc1_=cc0_^1;                                                      \
    float4 a_=*(const float4*)((bufptr)+(rr)*64+cc0_*4);                  \
    float4 b_=*(const float4*)((bufptr)+(rr)*64+cc1_*4);                  \
    xv[0]=a_.x; xv[1]=a_.y; xv[2]=a_.z; xv[3]=a_.w;                       \
    xv[4]=b_.x; xv[5]=b_.y; xv[6]=b_.z; xv[7]=b_.w;                       \
  }while(0)

// ---------------- kernels ----------------

__global__ void __launch_bounds__(256) initK(unsigned* ws){
  for(int i=blockIdx.x*256+threadIdx.x;i<ZERO_W;i+=gridDim.x*256) ws[i]=0u;
}

// global max of dd_k (single-f16). grid 512, 4 iters of 64 rows (P amortized).
__global__ void __launch_bounds__(256) stabK(const float* __restrict__ Kg,
                                             const float* __restrict__ Pg,
                                             unsigned* __restrict__ stab_ws){
  __shared__ float red[4];
  int tid=threadIdx.x, w=tid>>6, lane=tid&63, l15=lane&15, g=lane>>4;
  int fb=w*64;
  f16x8 pb[4][2];
  #pragma unroll
  for(int ft=0;ft<4;++ft)
    #pragma unroll
    for(int ks=0;ks<2;++ks){
      float x[8]; ld8(&Pg[(fb+16*ft+l15)*64+32*ks+8*g],x);
      #pragma unroll
      for(int i=0;i<8;++i) x[i]*=NRM;
      cvt8h(x,pb[ft][ks]);
    }
  float m=-3.4e38f;
  long base=(long)blockIdx.x*256;
  f32x4 zero={0.f,0.f,0.f,0.f};
  #pragma unroll 1
  for(int it=0;it<4;++it){
    long row0=base+it*64;
    f16x8 ka[4][2];
    #pragma unroll
    for(int rt=0;rt<4;++rt)
      #pragma unroll
      for(int ks=0;ks<2;++ks){
        float x[8]; ld8(&Kg[(row0+16*rt+l15)*64+32*ks+8*g],x);
        cvt8h(x,ka[rt][ks]);
      }
    f32x4 acc[4][4];
    #pragma unroll
    for(int rt=0;rt<4;++rt)
      #pragma unroll
      for(int ft=0;ft<4;++ft) acc[rt][ft]=zero;
    #pragma unroll
    for(int rt=0;rt<4;++rt)
      #pragma unroll
      for(int ft=0;ft<4;++ft)
        #pragma unroll
        for(int ks=0;ks<2;++ks)
          acc[rt][ft]=mfma16h(ka[rt][ks],pb[ft][ks],acc[rt][ft]);
    #pragma unroll
    for(int rt=0;rt<4;++rt)
      #pragma unroll
      for(int ft=0;ft<4;++ft)
        #pragma unroll
        for(int r=0;r<4;++r) m=fmaxf(m,acc[rt][ft][r]);
  }
  #pragma unroll
  for(int off=1;off<64;off<<=1) m=fmaxf(m,__shfl_xor(m,off));
  if(lane==0) red[w]=m;
  __syncthreads();
  if(tid==0){
    m=fmaxf(fmaxf(red[0],red[1]),fmaxf(red[2],red[3]));
    atomicMax(stab_ws,mapmax(m));
  }
}

// kp + ctx/ksum accumulation. grid = 512: 16 bh * 32 chunks of 256 rows,
// 8 iters. K LDS-staged dbuf, SINGLE bf16 in dd (1-pass); V reg-prefetched
// (split); P single bf16. setprio around MFMA clusters.
__global__ void __launch_bounds__(256,2) ctxK(const float* __restrict__ Kg,
    const float* __restrict__ Vg, const float* __restrict__ Pg,
    const unsigned* __restrict__ stab_ws, float* __restrict__ ctx_g,
    float* __restrict__ ksum_g, float* __restrict__ part, int mode){
  __shared__ __align__(16) bf16 kpt_h[256*40];   // 20KB
  __shared__ float kstage[2][2048];              // 2 x 8KB staged K tiles
  int tid=threadIdx.x, w=tid>>6, lane=tid&63, l15=lane&15, g=lane>>4;
  int fb=w*64;
  int bh=blockIdx.x>>5, ch=blockIdx.x&31;
  long rowbase=(long)bh*N_ + ch*256;
  float stab=unmapmax(*stab_ws);
  bf16x8 pb[4][2];
  load_P_frags1(Pg,fb,l15,g,pb);
  f32x4 zero={0.f,0.f,0.f,0.f};
  f32x4 cacc[4][4];
  #pragma unroll
  for(int mt=0;mt<4;++mt)
    #pragma unroll
    for(int et=0;et<4;++et) cacc[mt][et]=zero;
  float ksacc[4]={0.f,0.f,0.f,0.f};
  int cur=0;
  STAGE32(Kg, &kstage[0][0], rowbase);
  __syncthreads();                       // drain staging for iter 0
  #pragma unroll 1
  for(int it=0;it<8;++it){
    long n0=rowbase+it*32;
    long np=(it==7)? rowbase : n0+32;    // last iter: dummy re-stage (harmless)
    STAGE32(Kg, &kstage[cur^1][0], np);  // issue next K tile; lands by barrier
    // V raw prefetch (latency hidden under dd-GEMM + exp)
    float vx[4][8];
    #pragma unroll
    for(int et=0;et<4;++et)
      #pragma unroll
      for(int j=0;j<8;++j) vx[et][j]=Vg[(n0+8*g+j)*64+16*et+l15];
    // K a-frags (single bf16) + row sums of squares, from staged LDS
    bf16x8 ka[2][2];
    float dsq[2];
    #pragma unroll
    for(int rt=0;rt<2;++rt){
      float ss=0.f;
      #pragma unroll
      for(int ks=0;ks<2;++ks){
        float x[8]; FRAGREAD(x,&kstage[cur][0],16*rt+l15,ks);
        #pragma unroll
        for(int i=0;i<8;++i) ss=fmaf(x[i],x[i],ss);
        cvt8b(x,ka[rt][ks]);
      }
      ss+=__shfl_xor(ss,16); ss+=__shfl_xor(ss,32);
      dsq[rt]=DSC*ss;
    }
    // dd = K_b @ P_b (1-pass)
    f32x4 dacc[2][4];
    #pragma unroll
    for(int rt=0;rt<2;++rt)
      #pragma unroll
      for(int ft=0;ft<4;++ft) dacc[rt][ft]=zero;
    __builtin_amdgcn_s_setprio(1);
    #pragma unroll
    for(int rt=0;rt<2;++rt)
      #pragma unroll
      for(int ft=0;ft<4;++ft)
        #pragma unroll
        for(int ks=0;ks<2;++ks)
          dacc[rt][ft]=mfma16(ka[rt][ks],pb[ft][ks],dacc[rt][ft]);
    __builtin_amdgcn_s_setprio(0);
    float dg[2][4];
    #pragma unroll
    for(int rt=0;rt<2;++rt)
      #pragma unroll
      for(int r=0;r<4;++r) dg[rt][r]=__shfl(dsq[rt],4*g+r);
    // kp = RATIO*exp(dd - diag - stab) + REPS, rounded to bf16;
    // ksum accumulates the SAME rounded value (consistent features).
    #pragma unroll
    for(int rt=0;rt<2;++rt)
      #pragma unroll
      for(int ft=0;ft<4;++ft){
        int f=fb+16*ft+l15;
        #pragma unroll
        for(int r=0;r<4;++r){
          float kp=fmaf(RATIO,__expf(dacc[rt][ft][r]-dg[rt][r]-stab),REPS);
          bf16 hb=(bf16)kp;
          ksacc[ft]+=(float)hb;
          int nn=16*rt+4*g+r;
          kpt_h[f*40+nn]=hb;
        }
      }
    // V b-frags (split from prefetched registers)
    bf16x8 vb_h[4], vb_l[4];
    #pragma unroll
    for(int et=0;et<4;++et) split8(vx[et],vb_h[et],vb_l[et]);
    // ctx += kp_b^T @ V (kp single-plane x V split = 2-pass)
    __builtin_amdgcn_s_setprio(1);
    #pragma unroll
    for(int mt=0;mt<4;++mt){
      bf16x8 a_h=*(const bf16x8*)&kpt_h[(fb+16*mt+l15)*40+8*g];
      #pragma unroll
      for(int et=0;et<4;++et){
        cacc[mt][et]=mfma16(a_h,vb_h[et],cacc[mt][et]);
        cacc[mt][et]=mfma16(a_h,vb_l[et],cacc[mt][et]);
      }
    }
    __builtin_amdgcn_s_setprio(0);
    __syncthreads();   // kstage[cur] reads done; staging vmcnt drained
    cur^=1;
  }
  // ---- ksum cross-g reduce (both modes) ----
  float ksred[4];
  #pragma unroll
  for(int ft=0;ft<4;++ft){
    float s=ksacc[ft];
    s+=__shfl_xor(s,16); s+=__shfl_xor(s,32);
    ksred[ft]=s;
  }
  if(mode){
    float* cg=part+((long)ch*BH_+bh)*SLICE_W;
    #pragma unroll
    for(int mt=0;mt<4;++mt)
      #pragma unroll
      for(int et=0;et<4;++et)
        #pragma unroll
        for(int r=0;r<4;++r)
          cg[(fb+16*mt+4*g+r)*64+16*et+l15]=cacc[mt][et][r];
    if(g==0){
      #pragma unroll
      for(int ft=0;ft<4;++ft)
        cg[16384+fb+16*ft+l15]=ksred[ft];
    }
  }else{
    float* cg=ctx_g+(long)bh*16384;
    #pragma unroll
    for(int mt=0;mt<4;++mt)
      #pragma unroll
      for(int et=0;et<4;++et)
        #pragma unroll
        for(int r=0;r<4;++r)
          atomicAdd(&cg[(fb+16*mt+4*g+r)*64+16*et+l15],cacc[mt][et][r]);
    if(g==0){
      #pragma unroll
      for(int ft=0;ft<4;++ft)
        atomicAdd(&ksum_g[bh*256+fb+16*ft+l15],ksred[ft]);
    }
  }
}

// sum the 32 partial slices -> ctx / ksum. grid 520 x 256.
__global__ void __launch_bounds__(256) redK(const float* __restrict__ part,
    float* __restrict__ ctx_g, float* __restrict__ ksum_g){
  long t=(long)blockIdx.x*256+threadIdx.x;
  const long TOT=(long)BH_*SLICE_W;          // 266240
  for(long o=t;o<TOT;o+=(long)gridDim.x*256){
    int bh=(int)(o/SLICE_W), idx=(int)(o%SLICE_W);
    float s=0.f;
    #pragma unroll 8
    for(int ch=0;ch<32;++ch)
      s+=part[((long)ch*BH_+bh)*SLICE_W+idx];
    if(idx<16384) ctx_g[(long)bh*16384+idx]=s;
    else          ksum_g[bh*256+idx-16384]=s;
  }
}

// fused qp + out. grid = 512: 16 bh * 32 chunks of 256 rows, 4 fat iters of
// 64 rows. Q LDS-staged dbuf, SINGLE bf16 in dd (1-pass); DPP butterflies;
// qp single-bf16 ds_write_b16; ctx split. setprio around MFMA clusters.
__global__ void __launch_bounds__(256,2) qoK(const float* __restrict__ Qg,
    const float* __restrict__ Pg, const float* __restrict__ ctx_g,
    const float* __restrict__ ksum_g, float* __restrict__ outg){
  __shared__ float qstage[2][4096];          // 2 x 16KB staged Q tiles (swizzled)
  __shared__ __align__(16) bf16 qpt[64*264]; // bf16 qp plane, [n][f], stride 264
  __shared__ float rmaxl[4][64];
  __shared__ float denl[4][64];
  int tid=threadIdx.x, w=tid>>6, lane=tid&63, l15=lane&15, g=lane>>4;
  int fb=w*64;
  int bh=blockIdx.x>>5, ch=blockIdx.x&31;
  long rowbase=(long)bh*N_ + ch*256;

  bf16x8 pb[4][2];
  load_P_frags1(Pg,fb,l15,g,pb);
  float ksv[4];
  #pragma unroll
  for(int ft=0;ft<4;++ft) ksv[ft]=ksum_g[bh*256+fb+16*ft+l15];
  // ctx b-frags for this wave's e-tile (et = w), split
  bf16x8 cb_h[8], cb_l[8];
  #pragma unroll
  for(int ks=0;ks<8;++ks){
    float x[8];
    #pragma unroll
    for(int j=0;j<8;++j) x[j]=ctx_g[(long)bh*16384+(32*ks+8*g+j)*64+16*w+l15];
    split8(x,cb_h[ks],cb_l[ks]);
  }
  f32x4 zero={0.f,0.f,0.f,0.f};
  int cur=0;
  STAGE64(Qg, &qstage[0][0], rowbase);
  __syncthreads();                     // drain staging for iter 0
  #pragma unroll 1
  for(int it=0;it<4;++it){
    long n0=rowbase+it*64;
    long np=(it==3)? rowbase : n0+64;  // last iter: dummy re-stage (harmless)
    STAGE64(Qg, &qstage[cur^1][0], np);// issue next tile; lands by next barrier
    // dd per row-tile rt (qa single bf16, 1-pass)
    f32x4 dacc[4][4];
    float dsq[4];
    #pragma unroll
    for(int rt=0;rt<4;++rt){
      bf16x8 qa[2];
      float ss=0.f;
      #pragma unroll
      for(int ks=0;ks<2;++ks){
        float x[8]; FRAGREAD(x,&qstage[cur][0],16*rt+l15,ks);
        #pragma unroll
        for(int i=0;i<8;++i) ss=fmaf(x[i],x[i],ss);
        cvt8b(x,qa[ks]);
      }
      ss+=__shfl_xor(ss,16); ss+=__shfl_xor(ss,32);
      dsq[rt]=DSC*ss;
      #pragma unroll
      for(int ft=0;ft<4;++ft) dacc[rt][ft]=zero;
      __builtin_amdgcn_s_setprio(1);
      #pragma unroll
      for(int ft=0;ft<4;++ft)
        #pragma unroll
        for(int ks=0;ks<2;++ks)
          dacc[rt][ft]=mfma16(qa[ks],pb[ft][ks],dacc[rt][ft]);
      __builtin_amdgcn_s_setprio(0);
    }
    float dg[4][4];
    #pragma unroll
    for(int rt=0;rt<4;++rt)
      #pragma unroll
      for(int r=0;r<4;++r) dg[rt][r]=__shfl(dsq[rt],4*g+r);
    // per-wave rowmax over its f-strip (DPP butterfly, VALU pipe)
    #pragma unroll
    for(int rt=0;rt<4;++rt)
      #pragma unroll
      for(int r=0;r<4;++r){
        float m=fmaxf(fmaxf(dacc[rt][0][r],dacc[rt][1][r]),
                      fmaxf(dacc[rt][2][r],dacc[rt][3][r]));
        m=max16_dpp(m);
        if(l15==0) rmaxl[w][16*rt+4*g+r]=m;
      }
    __syncthreads();   // rowmax planes ready (also fences staging of cur^1)
    // qp (rounded bf16), den partials from the SAME rounded value,
    // direct b16 writes into qpt[n][f]; den reduce via DPP butterfly
    #pragma unroll
    for(int rt=0;rt<4;++rt)
      #pragma unroll
      for(int r=0;r<4;++r){
        int nn=16*rt+4*g+r;
        float rm=fmaxf(fmaxf(rmaxl[0][nn],rmaxl[1][nn]),
                       fmaxf(rmaxl[2][nn],rmaxl[3][nn]));
        float dp=0.f;
        #pragma unroll
        for(int ft=0;ft<4;++ft){
          float qp=fmaf(RATIO,__expf(dacc[rt][ft][r]-dg[rt][r]-rm),REPS);
          bf16 hb=(bf16)qp;
          dp=fmaf((float)hb,ksv[ft],dp);
          qpt[nn*264 + fb+16*ft+l15]=hb;
        }
        dp=sum16_dpp(dp);
        if(l15==0) denl[w][nn]=dp;
      }
    __syncthreads();   // qpt + denl ready
    // out = qp_b @ ctx (single-plane qp x split ctx = 2-pass)
    f32x4 oacc[4];
    #pragma unroll
    for(int mt=0;mt<4;++mt) oacc[mt]=zero;
    __builtin_amdgcn_s_setprio(1);
    #pragma unroll
    for(int ks=0;ks<8;++ks)
      #pragma unroll
      for(int mt=0;mt<4;++mt){
        bf16x8 a_h=*(const bf16x8*)&qpt[(16*mt+l15)*264+32*ks+8*g];
        oacc[mt]=mfma16(a_h,cb_h[ks],oacc[mt]);
        oacc[mt]=mfma16(a_h,cb_l[ks],oacc[mt]);
      }
    __builtin_amdgcn_s_setprio(0);
    #pragma unroll
    for(int mt=0;mt<4;++mt)
      #pragma unroll
      for(int r=0;r<4;++r){
        int nn=16*mt+4*g+r;
        float den=denl[0][nn]+denl[1][nn]+denl[2][nn]+denl[3][nn];
        float rden=__builtin_amdgcn_rcpf(den);
        outg[(n0+nn)*64+16*w+l15]=oacc[mt][r]*rden;
      }
    cur^=1;
  }
}

// ---------------- host ----------------

extern "C" void kernel_launch(void* const* d_in, const int* in_sizes, int n_in,
                              void* d_out, int out_size, void* d_ws, size_t ws_size,
                              hipStream_t stream) {
  (void)in_sizes; (void)n_in; (void)out_size;
  const float* q = (const float*)d_in[0];
  const float* k = (const float*)d_in[1];
  const float* v = (const float*)d_in[2];
  const float* P = (const float*)d_in[3];
  float* out = (float*)d_out;

  unsigned* stab = (unsigned*)d_ws;
  float* ctx  = (float*)d_ws + CTX_W;
  float* ksum = (float*)d_ws + KSUM_W;
  float* part = (float*)d_ws + PART_W;

  size_t need = ((size_t)PART_W + (size_t)32*BH_*SLICE_W) * 4;  // ~35.1 MB
  int mode = (ws_size >= need) ? 1 : 0;

  hipLaunchKernelGGL(initK, dim3(256), dim3(256), 0, stream, (unsigned*)d_ws);
  hipLaunchKernelGGL(stabK, dim3(512), dim3(256), 0, stream, k, P, stab);
  hipLaunchKernelGGL(ctxK, dim3(512), dim3(256), 0, stream, k, v, P, stab,
                     ctx, ksum, part, mode);
  if(mode)
    hipLaunchKernelGGL(redK, dim3(520), dim3(256), 0, stream, part, ctx, ksum);
  hipLaunchKernelGGL(qoK, dim3(512), dim3(256), 0, stream, q, P, ctx, ksum, out);
}

// Round 19
// 110.813 us; speedup vs baseline: 1.1793x; 1.0026x over previous
//
#include <hip/hip_runtime.h>

// Performer (FAVOR+) attention, MI355X, split-bf16 MFMA.
// B=2 H=8 N=8192 D=64 F=256; rows R = 131072.
// Round 19: instruction-count diet (r17 lesson: wave-level LDS-pipe issue
// count is the hidden cost class):
//  (a) ctxK kpt writes packed b16->b64 (4 r-values are thread-local,
//      nn consecutive): 32 -> 8 ds_write instrs/iter.
//  (b) initK mode-aware: in mode 1 redK fully overwrites ctx/ksum, so only
//      the 16-word stab header needs zeroing (was 1 MB/call).
//  (c) redK grid 520 -> 1040 (1 output/thread, halves serial add chain).
// r18 established: single-bf16 features (P,K,Q) consistent in num+den are
// ~free (absmax 3.66e-4); V/ctx stay split. qoK DPP butterflies (r17).

typedef __bf16 bf16;
typedef __bf16 bf16x8 __attribute__((ext_vector_type(8)));
typedef _Float16 f16;
typedef f16 f16x8 __attribute__((ext_vector_type(8)));
typedef float f32x4 __attribute__((ext_vector_type(4)));

#define N_    8192
#define BH_   16
#define NRM   0.35355339059327379f   // 64^-0.25
#define RATIO 0.0625f                // 256^-0.5
#define DSC   0.0625f                // 0.5*NRM^2
#define REPS  6.25e-6f               // RATIO*1e-4

#define CTX_W  16
#define KSUM_W (CTX_W + BH_*256*64)     // 262160
#define ZERO_W (KSUM_W + BH_*256)       // 266256
#define SLICE_W 16640                   // 16384 ctx + 256 ksum per (bh,ch)
#define PART_W  ZERO_W                  // partials start here (32*16*16640 w)

static __device__ __forceinline__ unsigned mapmax(float x){
  unsigned u=__float_as_uint(x); return (u&0x80000000u)? ~u : (u|0x80000000u);
}
static __device__ __forceinline__ float unmapmax(unsigned u){
  return __uint_as_float((u&0x80000000u)? (u&0x7fffffffu) : ~u);
}
static __device__ __forceinline__ f32x4 mfma16(bf16x8 a, bf16x8 b, f32x4 c){
  return __builtin_amdgcn_mfma_f32_16x16x32_bf16(a,b,c,0,0,0);
}
static __device__ __forceinline__ f32x4 mfma16h(f16x8 a, f16x8 b, f32x4 c){
  return __builtin_amdgcn_mfma_f32_16x16x32_f16(a,b,c,0,0,0);
}
// DPP lane permute within aligned 16-lane rows (VALU pipe, no LDS).
template<int CTRL>
static __device__ __forceinline__ float dppf(float x){
  int v=__builtin_amdgcn_update_dpp(0, __float_as_int(x), CTRL, 0xF, 0xF, true);
  return __int_as_float(v);
}
static __device__ __forceinline__ float max16_dpp(float x){
  x=fmaxf(x,dppf<0xB1>(x));  // quad_perm [1,0,3,2]
  x=fmaxf(x,dppf<0x4E>(x));  // quad_perm [2,3,0,1]
  x=fmaxf(x,dppf<0x141>(x)); // row_half_mirror
  x=fmaxf(x,dppf<0x140>(x)); // row_mirror
  return x;
}
static __device__ __forceinline__ float sum16_dpp(float x){
  x+=dppf<0xB1>(x);
  x+=dppf<0x4E>(x);
  x+=dppf<0x141>(x);
  x+=dppf<0x140>(x);
  return x;
}
static __device__ __forceinline__ void ld8(const float* __restrict__ p, float* x){
  float4 a=*(const float4*)p; float4 b=*(const float4*)(p+4);
  x[0]=a.x; x[1]=a.y; x[2]=a.z; x[3]=a.w; x[4]=b.x; x[5]=b.y; x[6]=b.z; x[7]=b.w;
}
static __device__ __forceinline__ void split8(const float* x, bf16x8& h, bf16x8& l){
  #pragma unroll
  for(int i=0;i<8;++i){ bf16 hi=(bf16)x[i]; h[i]=hi; l[i]=(bf16)(x[i]-(float)hi); }
}
static __device__ __forceinline__ void cvt8b(const float* x, bf16x8& h){
  #pragma unroll
  for(int i=0;i<8;++i) h[i]=(bf16)x[i];
}
static __device__ __forceinline__ void cvt8h(const float* x, f16x8& h){
  #pragma unroll
  for(int i=0;i<8;++i) h[i]=(f16)x[i];
}
static __device__ __forceinline__ void gload16(const float* g, float* l){
  __builtin_amdgcn_global_load_lds(
      (const __attribute__((address_space(1))) unsigned*)g,
      (__attribute__((address_space(3))) unsigned*)l, 16, 0, 0);
}
// P-hat (NRM*P) b-fragments, SINGLE bf16 plane: [ft 0..3][ks 0..1]
static __device__ __forceinline__ void load_P_frags1(const float* __restrict__ Pg,
    int fb, int l15, int g, bf16x8 (&pb)[4][2]){
  #pragma unroll
  for(int ft=0;ft<4;++ft)
    #pragma unroll
    for(int ks=0;ks<2;++ks){
      float x[8]; ld8(&Pg[(fb+16*ft+l15)*64+32*ks+8*g],x);
      #pragma unroll
      for(int i=0;i<8;++i) x[i]*=NRM;
      cvt8b(x,pb[ft][ks]);
    }
}

// stage 32 rows x 64 floats from Xg into LDS buf, source XOR-swizzled by
// row&15 so fragment-pattern b128 reads are conflict-free (r9 pattern).
#define STAGE32(Xg, bufptr, n0s) do{                                      \
    int u0_=tid, u1_=tid+256;                                             \
    int r0_=u0_>>4, c0_=u0_&15, r1_=u1_>>4, c1_=u1_&15;                   \
    gload16((Xg)+((n0s)+r0_)*64+((c0_^(r0_&15))<<2), (bufptr)+u0_*4);     \
    gload16((Xg)+((n0s)+r1_)*64+((c1_^(r1_&15))<<2), (bufptr)+u1_*4);     \
  }while(0)
// stage 64 rows x 64 floats (qoK fat iters)
#define STAGE64(Xg, bufptr, n0s) do{                                      \
    _Pragma("unroll")                                                     \
    for(int ii_=0;ii_<4;++ii_){                                           \
      int u_=tid+256*ii_;                                                 \
      int r_=u_>>4, c_=u_&15;                                             \
      gload16((Xg)+((n0s)+r_)*64+((c_^(r_&15))<<2), (bufptr)+u_*4);       \
    }                                                                     \
  }while(0)
// x[8] <- staged row rr, k-chunk ks (two swizzled b128 reads)
#define FRAGREAD(xv, bufptr, rr, ksv) do{                                 \
    int cc0_=(8*(ksv)+2*g)^((rr)&15);                                     \
    int cc1_=cc0_^1;                                                      \
    float4 a_=*(const float4*)((bufptr)+(rr)*64+cc0_*4);                  \
    float4 b_=*(const float4*)((bufptr)+(rr)*64+cc1_*4);                  \
    xv[0]=a_.x; xv[1]=a_.y; xv[2]=a_.z; xv[3]=a_.w;                       \
    xv[4]=b_.x; xv[5]=b_.y; xv[6]=b_.z; xv[7]=b_.w;                       \
  }while(0)

// ---------------- kernels ----------------

__global__ void __launch_bounds__(256) initK(unsigned* ws, int n){
  for(int i=blockIdx.x*256+threadIdx.x;i<n;i+=gridDim.x*256) ws[i]=0u;
}

// global max of dd_k (single-f16). grid 512, 4 iters of 64 rows (P amortized).
__global__ void __launch_bounds__(256) stabK(const float* __restrict__ Kg,
                                             const float* __restrict__ Pg,
                                             unsigned* __restrict__ stab_ws){
  __shared__ float red[4];
  int tid=threadIdx.x, w=tid>>6, lane=tid&63, l15=lane&15, g=lane>>4;
  int fb=w*64;
  f16x8 pb[4][2];
  #pragma unroll
  for(int ft=0;ft<4;++ft)
    #pragma unroll
    for(int ks=0;ks<2;++ks){
      float x[8]; ld8(&Pg[(fb+16*ft+l15)*64+32*ks+8*g],x);
      #pragma unroll
      for(int i=0;i<8;++i) x[i]*=NRM;
      cvt8h(x,pb[ft][ks]);
    }
  float m=-3.4e38f;
  long base=(long)blockIdx.x*256;
  f32x4 zero={0.f,0.f,0.f,0.f};
  #pragma unroll 1
  for(int it=0;it<4;++it){
    long row0=base+it*64;
    f16x8 ka[4][2];
    #pragma unroll
    for(int rt=0;rt<4;++rt)
      #pragma unroll
      for(int ks=0;ks<2;++ks){
        float x[8]; ld8(&Kg[(row0+16*rt+l15)*64+32*ks+8*g],x);
        cvt8h(x,ka[rt][ks]);
      }
    f32x4 acc[4][4];
    #pragma unroll
    for(int rt=0;rt<4;++rt)
      #pragma unroll
      for(int ft=0;ft<4;++ft) acc[rt][ft]=zero;
    #pragma unroll
    for(int rt=0;rt<4;++rt)
      #pragma unroll
      for(int ft=0;ft<4;++ft)
        #pragma unroll
        for(int ks=0;ks<2;++ks)
          acc[rt][ft]=mfma16h(ka[rt][ks],pb[ft][ks],acc[rt][ft]);
    #pragma unroll
    for(int rt=0;rt<4;++rt)
      #pragma unroll
      for(int ft=0;ft<4;++ft)
        #pragma unroll
        for(int r=0;r<4;++r) m=fmaxf(m,acc[rt][ft][r]);
  }
  #pragma unroll
  for(int off=1;off<64;off<<=1) m=fmaxf(m,__shfl_xor(m,off));
  if(lane==0) red[w]=m;
  __syncthreads();
  if(tid==0){
    m=fmaxf(fmaxf(red[0],red[1]),fmaxf(red[2],red[3]));
    atomicMax(stab_ws,mapmax(m));
  }
}

// kp + ctx/ksum accumulation. grid = 512: 16 bh * 32 chunks of 256 rows,
// 8 iters. K LDS-staged dbuf, SINGLE bf16 in dd (1-pass); V reg-prefetched
// (split); P single bf16. kpt writes packed b64 (thread-local 4x bf16).
__global__ void __launch_bounds__(256,2) ctxK(const float* __restrict__ Kg,
    const float* __restrict__ Vg, const float* __restrict__ Pg,
    const unsigned* __restrict__ stab_ws, float* __restrict__ ctx_g,
    float* __restrict__ ksum_g, float* __restrict__ part, int mode){
  __shared__ __align__(16) bf16 kpt_h[256*40];   // 20KB
  __shared__ float kstage[2][2048];              // 2 x 8KB staged K tiles
  int tid=threadIdx.x, w=tid>>6, lane=tid&63, l15=lane&15, g=lane>>4;
  int fb=w*64;
  int bh=blockIdx.x>>5, ch=blockIdx.x&31;
  long rowbase=(long)bh*N_ + ch*256;
  float stab=unmapmax(*stab_ws);
  bf16x8 pb[4][2];
  load_P_frags1(Pg,fb,l15,g,pb);
  f32x4 zero={0.f,0.f,0.f,0.f};
  f32x4 cacc[4][4];
  #pragma unroll
  for(int mt=0;mt<4;++mt)
    #pragma unroll
    for(int et=0;et<4;++et) cacc[mt][et]=zero;
  float ksacc[4]={0.f,0.f,0.f,0.f};
  int cur=0;
  STAGE32(Kg, &kstage[0][0], rowbase);
  __syncthreads();                       // drain staging for iter 0
  #pragma unroll 1
  for(int it=0;it<8;++it){
    long n0=rowbase+it*32;
    long np=(it==7)? rowbase : n0+32;    // last iter: dummy re-stage (harmless)
    STAGE32(Kg, &kstage[cur^1][0], np);  // issue next K tile; lands by barrier
    // V raw prefetch (latency hidden under dd-GEMM + exp)
    float vx[4][8];
    #pragma unroll
    for(int et=0;et<4;++et)
      #pragma unroll
      for(int j=0;j<8;++j) vx[et][j]=Vg[(n0+8*g+j)*64+16*et+l15];
    // K a-frags (single bf16) + row sums of squares, from staged LDS
    bf16x8 ka[2][2];
    float dsq[2];
    #pragma unroll
    for(int rt=0;rt<2;++rt){
      float ss=0.f;
      #pragma unroll
      for(int ks=0;ks<2;++ks){
        float x[8]; FRAGREAD(x,&kstage[cur][0],16*rt+l15,ks);
        #pragma unroll
        for(int i=0;i<8;++i) ss=fmaf(x[i],x[i],ss);
        cvt8b(x,ka[rt][ks]);
      }
      ss+=__shfl_xor(ss,16); ss+=__shfl_xor(ss,32);
      dsq[rt]=DSC*ss;
    }
    // dd = K_b @ P_b (1-pass)
    f32x4 dacc[2][4];
    #pragma unroll
    for(int rt=0;rt<2;++rt)
      #pragma unroll
      for(int ft=0;ft<4;++ft) dacc[rt][ft]=zero;
    __builtin_amdgcn_s_setprio(1);
    #pragma unroll
    for(int rt=0;rt<2;++rt)
      #pragma unroll
      for(int ft=0;ft<4;++ft)
        #pragma unroll
        for(int ks=0;ks<2;++ks)
          dacc[rt][ft]=mfma16(ka[rt][ks],pb[ft][ks],dacc[rt][ft]);
    __builtin_amdgcn_s_setprio(0);
    float dg[2][4];
    #pragma unroll
    for(int rt=0;rt<2;++rt)
      #pragma unroll
      for(int r=0;r<4;++r) dg[rt][r]=__shfl(dsq[rt],4*g+r);
    // kp = RATIO*exp(dd - diag - stab) + REPS, rounded to bf16;
    // ksum accumulates the SAME rounded value. Packed b64 writes:
    // the 4 r-values are thread-local and nn-consecutive (nn=16rt+4g+r).
    #pragma unroll
    for(int rt=0;rt<2;++rt)
      #pragma unroll
      for(int ft=0;ft<4;++ft){
        int f=fb+16*ft+l15;
        ushort4 pk;
        unsigned short hvb[4];
        #pragma unroll
        for(int r=0;r<4;++r){
          float kp=fmaf(RATIO,__expf(dacc[rt][ft][r]-dg[rt][r]-stab),REPS);
          bf16 hb=(bf16)kp;
          ksacc[ft]+=(float)hb;
          hvb[r]=__builtin_bit_cast(unsigned short,hb);
        }
        pk.x=hvb[0]; pk.y=hvb[1]; pk.z=hvb[2]; pk.w=hvb[3];
        *(ushort4*)&kpt_h[f*40+16*rt+4*g]=pk;
      }
    // V b-frags (split from prefetched registers)
    bf16x8 vb_h[4], vb_l[4];
    #pragma unroll
    for(int et=0;et<4;++et) split8(vx[et],vb_h[et],vb_l[et]);
    // ctx += kp_b^T @ V (kp single-plane x V split = 2-pass)
    __builtin_amdgcn_s_setprio(1);
    #pragma unroll
    for(int mt=0;mt<4;++mt){
      bf16x8 a_h=*(const bf16x8*)&kpt_h[(fb+16*mt+l15)*40+8*g];
      #pragma unroll
      for(int et=0;et<4;++et){
        cacc[mt][et]=mfma16(a_h,vb_h[et],cacc[mt][et]);
        cacc[mt][et]=mfma16(a_h,vb_l[et],cacc[mt][et]);
      }
    }
    __builtin_amdgcn_s_setprio(0);
    __syncthreads();   // kstage[cur] reads done; staging vmcnt drained
    cur^=1;
  }
  // ---- ksum cross-g reduce (both modes) ----
  float ksred[4];
  #pragma unroll
  for(int ft=0;ft<4;++ft){
    float s=ksacc[ft];
    s+=__shfl_xor(s,16); s+=__shfl_xor(s,32);
    ksred[ft]=s;
  }
  if(mode){
    float* cg=part+((long)ch*BH_+bh)*SLICE_W;
    #pragma unroll
    for(int mt=0;mt<4;++mt)
      #pragma unroll
      for(int et=0;et<4;++et)
        #pragma unroll
        for(int r=0;r<4;++r)
          cg[(fb+16*mt+4*g+r)*64+16*et+l15]=cacc[mt][et][r];
    if(g==0){
      #pragma unroll
      for(int ft=0;ft<4;++ft)
        cg[16384+fb+16*ft+l15]=ksred[ft];
    }
  }else{
    float* cg=ctx_g+(long)bh*16384;
    #pragma unroll
    for(int mt=0;mt<4;++mt)
      #pragma unroll
      for(int et=0;et<4;++et)
        #pragma unroll
        for(int r=0;r<4;++r)
          atomicAdd(&cg[(fb+16*mt+4*g+r)*64+16*et+l15],cacc[mt][et][r]);
    if(g==0){
      #pragma unroll
      for(int ft=0;ft<4;++ft)
        atomicAdd(&ksum_g[bh*256+fb+16*ft+l15],ksred[ft]);
    }
  }
}

// sum the 32 partial slices -> ctx / ksum. grid 1040 x 256 (1 output/thread).
__global__ void __launch_bounds__(256) redK(const float* __restrict__ part,
    float* __restrict__ ctx_g, float* __restrict__ ksum_g){
  long t=(long)blockIdx.x*256+threadIdx.x;
  const long TOT=(long)BH_*SLICE_W;          // 266240
  for(long o=t;o<TOT;o+=(long)gridDim.x*256){
    int bh=(int)(o/SLICE_W), idx=(int)(o%SLICE_W);
    float s=0.f;
    #pragma unroll 8
    for(int ch=0;ch<32;++ch)
      s+=part[((long)ch*BH_+bh)*SLICE_W+idx];
    if(idx<16384) ctx_g[(long)bh*16384+idx]=s;
    else          ksum_g[bh*256+idx-16384]=s;
  }
}

// fused qp + out. grid = 512: 16 bh * 32 chunks of 256 rows, 4 fat iters of
// 64 rows. Q LDS-staged dbuf, SINGLE bf16 in dd (1-pass); DPP butterflies;
// qp single-bf16 ds_write_b16; ctx split. setprio around MFMA clusters.
__global__ void __launch_bounds__(256,2) qoK(const float* __restrict__ Qg,
    const float* __restrict__ Pg, const float* __restrict__ ctx_g,
    const float* __restrict__ ksum_g, float* __restrict__ outg){
  __shared__ float qstage[2][4096];          // 2 x 16KB staged Q tiles (swizzled)
  __shared__ __align__(16) bf16 qpt[64*264]; // bf16 qp plane, [n][f], stride 264
  __shared__ float rmaxl[4][64];
  __shared__ float denl[4][64];
  int tid=threadIdx.x, w=tid>>6, lane=tid&63, l15=lane&15, g=lane>>4;
  int fb=w*64;
  int bh=blockIdx.x>>5, ch=blockIdx.x&31;
  long rowbase=(long)bh*N_ + ch*256;

  bf16x8 pb[4][2];
  load_P_frags1(Pg,fb,l15,g,pb);
  float ksv[4];
  #pragma unroll
  for(int ft=0;ft<4;++ft) ksv[ft]=ksum_g[bh*256+fb+16*ft+l15];
  // ctx b-frags for this wave's e-tile (et = w), split
  bf16x8 cb_h[8], cb_l[8];
  #pragma unroll
  for(int ks=0;ks<8;++ks){
    float x[8];
    #pragma unroll
    for(int j=0;j<8;++j) x[j]=ctx_g[(long)bh*16384+(32*ks+8*g+j)*64+16*w+l15];
    split8(x,cb_h[ks],cb_l[ks]);
  }
  f32x4 zero={0.f,0.f,0.f,0.f};
  int cur=0;
  STAGE64(Qg, &qstage[0][0], rowbase);
  __syncthreads();                     // drain staging for iter 0
  #pragma unroll 1
  for(int it=0;it<4;++it){
    long n0=rowbase+it*64;
    long np=(it==3)? rowbase : n0+64;  // last iter: dummy re-stage (harmless)
    STAGE64(Qg, &qstage[cur^1][0], np);// issue next tile; lands by next barrier
    // dd per row-tile rt (qa single bf16, 1-pass)
    f32x4 dacc[4][4];
    float dsq[4];
    #pragma unroll
    for(int rt=0;rt<4;++rt){
      bf16x8 qa[2];
      float ss=0.f;
      #pragma unroll
      for(int ks=0;ks<2;++ks){
        float x[8]; FRAGREAD(x,&qstage[cur][0],16*rt+l15,ks);
        #pragma unroll
        for(int i=0;i<8;++i) ss=fmaf(x[i],x[i],ss);
        cvt8b(x,qa[ks]);
      }
      ss+=__shfl_xor(ss,16); ss+=__shfl_xor(ss,32);
      dsq[rt]=DSC*ss;
      #pragma unroll
      for(int ft=0;ft<4;++ft) dacc[rt][ft]=zero;
      __builtin_amdgcn_s_setprio(1);
      #pragma unroll
      for(int ft=0;ft<4;++ft)
        #pragma unroll
        for(int ks=0;ks<2;++ks)
          dacc[rt][ft]=mfma16(qa[ks],pb[ft][ks],dacc[rt][ft]);
      __builtin_amdgcn_s_setprio(0);
    }
    float dg[4][4];
    #pragma unroll
    for(int rt=0;rt<4;++rt)
      #pragma unroll
      for(int r=0;r<4;++r) dg[rt][r]=__shfl(dsq[rt],4*g+r);
    // per-wave rowmax over its f-strip (DPP butterfly, VALU pipe)
    #pragma unroll
    for(int rt=0;rt<4;++rt)
      #pragma unroll
      for(int r=0;r<4;++r){
        float m=fmaxf(fmaxf(dacc[rt][0][r],dacc[rt][1][r]),
                      fmaxf(dacc[rt][2][r],dacc[rt][3][r]));
        m=max16_dpp(m);
        if(l15==0) rmaxl[w][16*rt+4*g+r]=m;
      }
    __syncthreads();   // rowmax planes ready (also fences staging of cur^1)
    // qp (rounded bf16), den partials from the SAME rounded value,
    // direct b16 writes into qpt[n][f]; den reduce via DPP butterfly
    #pragma unroll
    for(int rt=0;rt<4;++rt)
      #pragma unroll
      for(int r=0;r<4;++r){
        int nn=16*rt+4*g+r;
        float rm=fmaxf(fmaxf(rmaxl[0][nn],rmaxl[1][nn]),
                       fmaxf(rmaxl[2][nn],rmaxl[3][nn]));
        float dp=0.f;
        #pragma unroll
        for(int ft=0;ft<4;++ft){
          float qp=fmaf(RATIO,__expf(dacc[rt][ft][r]-dg[rt][r]-rm),REPS);
          bf16 hb=(bf16)qp;
          dp=fmaf((float)hb,ksv[ft],dp);
          qpt[nn*264 + fb+16*ft+l15]=hb;
        }
        dp=sum16_dpp(dp);
        if(l15==0) denl[w][nn]=dp;
      }
    __syncthreads();   // qpt + denl ready
    // out = qp_b @ ctx (single-plane qp x split ctx = 2-pass)
    f32x4 oacc[4];
    #pragma unroll
    for(int mt=0;mt<4;++mt) oacc[mt]=zero;
    __builtin_amdgcn_s_setprio(1);
    #pragma unroll
    for(int ks=0;ks<8;++ks)
      #pragma unroll
      for(int mt=0;mt<4;++mt){
        bf16x8 a_h=*(const bf16x8*)&qpt[(16*mt+l15)*264+32*ks+8*g];
        oacc[mt]=mfma16(a_h,cb_h[ks],oacc[mt]);
        oacc[mt]=mfma16(a_h,cb_l[ks],oacc[mt]);
      }
    __builtin_amdgcn_s_setprio(0);
    #pragma unroll
    for(int mt=0;mt<4;++mt)
      #pragma unroll
      for(int r=0;r<4;++r){
        int nn=16*mt+4*g+r;
        float den=denl[0][nn]+denl[1][nn]+denl[2][nn]+denl[3][nn];
        float rden=__builtin_amdgcn_rcpf(den);
        outg[(n0+nn)*64+16*w+l15]=oacc[mt][r]*rden;
      }
    cur^=1;
  }
}

// ---------------- host ----------------

extern "C" void kernel_launch(void* const* d_in, const int* in_sizes, int n_in,
                              void* d_out, int out_size, void* d_ws, size_t ws_size,
                              hipStream_t stream) {
  (void)in_sizes; (void)n_in; (void)out_size;
  const float* q = (const float*)d_in[0];
  const float* k = (const float*)d_in[1];
  const float* v = (const float*)d_in[2];
  const float* P = (const float*)d_in[3];
  float* out = (float*)d_out;

  unsigned* stab = (unsigned*)d_ws;
  float* ctx  = (float*)d_ws + CTX_W;
  float* ksum = (float*)d_ws + KSUM_W;
  float* part = (float*)d_ws + PART_W;

  size_t need = ((size_t)PART_W + (size_t)32*BH_*SLICE_W) * 4;  // ~35.1 MB
  int mode = (ws_size >= need) ? 1 : 0;

  // mode 1: redK fully overwrites ctx/ksum -> only stab header needs zeroing
  if(mode)
    hipLaunchKernelGGL(initK, dim3(1), dim3(256), 0, stream, (unsigned*)d_ws, CTX_W);
  else
    hipLaunchKernelGGL(initK, dim3(256), dim3(256), 0, stream, (unsigned*)d_ws, ZERO_W);
  hipLaunchKernelGGL(stabK, dim3(512), dim3(256), 0, stream, k, P, stab);
  hipLaunchKernelGGL(ctxK, dim3(512), dim3(256), 0, stream, k, v, P, stab,
                     ctx, ksum, part, mode);
  if(mode)
    hipLaunchKernelGGL(redK, dim3(1040), dim3(256), 0, stream, part, ctx, ksum);
  hipLaunchKernelGGL(qoK, dim3(512), dim3(256), 0, stream, q, P, ctx, ksum, out);
}

// Round 20
// 105.799 us; speedup vs baseline: 1.2352x; 1.0474x over previous
//
#include <hip/hip_runtime.h>

// Performer (FAVOR+) attention, MI355X, split-bf16 MFMA.
// B=2 H=8 N=8192 D=64 F=256; rows R = 131072.
// Round 20 (qoK only): SWAPPED-OPERAND dd — mfma16(pb,qa) computes dd^T
// (row=f=16ft+4g+r, col=n=16rt+l15) with the SAME registers (A/B frag
// per-lane layouts coincide). Wins: dg shfl-gather gone (diag already
// per-l15), qpt writes 64 scalar b16 -> 16 packed ushort4 (r = 4
// consecutive f), rowmax/den = local 16-max + 2 shfls (was 4-deep DPP x16),
// rmaxl reads 64->16, ksum as 4x float4. PV/barriers/LDS unchanged.
// ctxK/stabK/redK unchanged from r19 (controls).

typedef __bf16 bf16;
typedef __bf16 bf16x8 __attribute__((ext_vector_type(8)));
typedef _Float16 f16;
typedef f16 f16x8 __attribute__((ext_vector_type(8)));
typedef float f32x4 __attribute__((ext_vector_type(4)));

#define N_    8192
#define BH_   16
#define NRM   0.35355339059327379f   // 64^-0.25
#define RATIO 0.0625f                // 256^-0.5
#define DSC   0.0625f                // 0.5*NRM^2
#define REPS  6.25e-6f               // RATIO*1e-4

#define CTX_W  16
#define KSUM_W (CTX_W + BH_*256*64)     // 262160
#define ZERO_W (KSUM_W + BH_*256)       // 266256
#define SLICE_W 16640                   // 16384 ctx + 256 ksum per (bh,ch)
#define PART_W  ZERO_W                  // partials start here (32*16*16640 w)

static __device__ __forceinline__ unsigned mapmax(float x){
  unsigned u=__float_as_uint(x); return (u&0x80000000u)? ~u : (u|0x80000000u);
}
static __device__ __forceinline__ float unmapmax(unsigned u){
  return __uint_as_float((u&0x80000000u)? (u&0x7fffffffu) : ~u);
}
static __device__ __forceinline__ f32x4 mfma16(bf16x8 a, bf16x8 b, f32x4 c){
  return __builtin_amdgcn_mfma_f32_16x16x32_bf16(a,b,c,0,0,0);
}
static __device__ __forceinline__ f32x4 mfma16h(f16x8 a, f16x8 b, f32x4 c){
  return __builtin_amdgcn_mfma_f32_16x16x32_f16(a,b,c,0,0,0);
}
static __device__ __forceinline__ void ld8(const float* __restrict__ p, float* x){
  float4 a=*(const float4*)p; float4 b=*(const float4*)(p+4);
  x[0]=a.x; x[1]=a.y; x[2]=a.z; x[3]=a.w; x[4]=b.x; x[5]=b.y; x[6]=b.z; x[7]=b.w;
}
static __device__ __forceinline__ void split8(const float* x, bf16x8& h, bf16x8& l){
  #pragma unroll
  for(int i=0;i<8;++i){ bf16 hi=(bf16)x[i]; h[i]=hi; l[i]=(bf16)(x[i]-(float)hi); }
}
static __device__ __forceinline__ void cvt8b(const float* x, bf16x8& h){
  #pragma unroll
  for(int i=0;i<8;++i) h[i]=(bf16)x[i];
}
static __device__ __forceinline__ void cvt8h(const float* x, f16x8& h){
  #pragma unroll
  for(int i=0;i<8;++i) h[i]=(f16)x[i];
}
static __device__ __forceinline__ void gload16(const float* g, float* l){
  __builtin_amdgcn_global_load_lds(
      (const __attribute__((address_space(1))) unsigned*)g,
      (__attribute__((address_space(3))) unsigned*)l, 16, 0, 0);
}
// P-hat (NRM*P) b-fragments, SINGLE bf16 plane: [ft 0..3][ks 0..1]
static __device__ __forceinline__ void load_P_frags1(const float* __restrict__ Pg,
    int fb, int l15, int g, bf16x8 (&pb)[4][2]){
  #pragma unroll
  for(int ft=0;ft<4;++ft)
    #pragma unroll
    for(int ks=0;ks<2;++ks){
      float x[8]; ld8(&Pg[(fb+16*ft+l15)*64+32*ks+8*g],x);
      #pragma unroll
      for(int i=0;i<8;++i) x[i]*=NRM;
      cvt8b(x,pb[ft][ks]);
    }
}

// stage 32 rows x 64 floats from Xg into LDS buf, source XOR-swizzled by
// row&15 so fragment-pattern b128 reads are conflict-free (r9 pattern).
#define STAGE32(Xg, bufptr, n0s) do{                                      \
    int u0_=tid, u1_=tid+256;                                             \
    int r0_=u0_>>4, c0_=u0_&15, r1_=u1_>>4, c1_=u1_&15;                   \
    gload16((Xg)+((n0s)+r0_)*64+((c0_^(r0_&15))<<2), (bufptr)+u0_*4);     \
    gload16((Xg)+((n0s)+r1_)*64+((c1_^(r1_&15))<<2), (bufptr)+u1_*4);     \
  }while(0)
// stage 64 rows x 64 floats (qoK fat iters)
#define STAGE64(Xg, bufptr, n0s) do{                                      \
    _Pragma("unroll")                                                     \
    for(int ii_=0;ii_<4;++ii_){                                           \
      int u_=tid+256*ii_;                                                 \
      int r_=u_>>4, c_=u_&15;                                             \
      gload16((Xg)+((n0s)+r_)*64+((c_^(r_&15))<<2), (bufptr)+u_*4);       \
    }                                                                     \
  }while(0)
// x[8] <- staged row rr, k-chunk ks (two swizzled b128 reads)
#define FRAGREAD(xv, bufptr, rr, ksv) do{                                 \
    int cc0_=(8*(ksv)+2*g)^((rr)&15);                                     \
    int cc1_=cc0_^1;                                                      \
    float4 a_=*(const float4*)((bufptr)+(rr)*64+cc0_*4);                  \
    float4 b_=*(const float4*)((bufptr)+(rr)*64+cc1_*4);                  \
    xv[0]=a_.x; xv[1]=a_.y; xv[2]=a_.z; xv[3]=a_.w;                       \
    xv[4]=b_.x; xv[5]=b_.y; xv[6]=b_.z; xv[7]=b_.w;                       \
  }while(0)

// ---------------- kernels ----------------

__global__ void __launch_bounds__(256) initK(unsigned* ws, int n){
  for(int i=blockIdx.x*256+threadIdx.x;i<n;i+=gridDim.x*256) ws[i]=0u;
}

// global max of dd_k (single-f16). grid 512, 4 iters of 64 rows (P amortized).
__global__ void __launch_bounds__(256) stabK(const float* __restrict__ Kg,
                                             const float* __restrict__ Pg,
                                             unsigned* __restrict__ stab_ws){
  __shared__ float red[4];
  int tid=threadIdx.x, w=tid>>6, lane=tid&63, l15=lane&15, g=lane>>4;
  int fb=w*64;
  f16x8 pb[4][2];
  #pragma unroll
  for(int ft=0;ft<4;++ft)
    #pragma unroll
    for(int ks=0;ks<2;++ks){
      float x[8]; ld8(&Pg[(fb+16*ft+l15)*64+32*ks+8*g],x);
      #pragma unroll
      for(int i=0;i<8;++i) x[i]*=NRM;
      cvt8h(x,pb[ft][ks]);
    }
  float m=-3.4e38f;
  long base=(long)blockIdx.x*256;
  f32x4 zero={0.f,0.f,0.f,0.f};
  #pragma unroll 1
  for(int it=0;it<4;++it){
    long row0=base+it*64;
    f16x8 ka[4][2];
    #pragma unroll
    for(int rt=0;rt<4;++rt)
      #pragma unroll
      for(int ks=0;ks<2;++ks){
        float x[8]; ld8(&Kg[(row0+16*rt+l15)*64+32*ks+8*g],x);
        cvt8h(x,ka[rt][ks]);
      }
    f32x4 acc[4][4];
    #pragma unroll
    for(int rt=0;rt<4;++rt)
      #pragma unroll
      for(int ft=0;ft<4;++ft) acc[rt][ft]=zero;
    #pragma unroll
    for(int rt=0;rt<4;++rt)
      #pragma unroll
      for(int ft=0;ft<4;++ft)
        #pragma unroll
        for(int ks=0;ks<2;++ks)
          acc[rt][ft]=mfma16h(ka[rt][ks],pb[ft][ks],acc[rt][ft]);
    #pragma unroll
    for(int rt=0;rt<4;++rt)
      #pragma unroll
      for(int ft=0;ft<4;++ft)
        #pragma unroll
        for(int r=0;r<4;++r) m=fmaxf(m,acc[rt][ft][r]);
  }
  #pragma unroll
  for(int off=1;off<64;off<<=1) m=fmaxf(m,__shfl_xor(m,off));
  if(lane==0) red[w]=m;
  __syncthreads();
  if(tid==0){
    m=fmaxf(fmaxf(red[0],red[1]),fmaxf(red[2],red[3]));
    atomicMax(stab_ws,mapmax(m));
  }
}

// kp + ctx/ksum accumulation. grid = 512: 16 bh * 32 chunks of 256 rows,
// 8 iters. K LDS-staged dbuf, SINGLE bf16 in dd (1-pass); V reg-prefetched
// (split); P single bf16. kpt writes packed b64. UNCHANGED from r19.
__global__ void __launch_bounds__(256,2) ctxK(const float* __restrict__ Kg,
    const float* __restrict__ Vg, const float* __restrict__ Pg,
    const unsigned* __restrict__ stab_ws, float* __restrict__ ctx_g,
    float* __restrict__ ksum_g, float* __restrict__ part, int mode){
  __shared__ __align__(16) bf16 kpt_h[256*40];   // 20KB
  __shared__ float kstage[2][2048];              // 2 x 8KB staged K tiles
  int tid=threadIdx.x, w=tid>>6, lane=tid&63, l15=lane&15, g=lane>>4;
  int fb=w*64;
  int bh=blockIdx.x>>5, ch=blockIdx.x&31;
  long rowbase=(long)bh*N_ + ch*256;
  float stab=unmapmax(*stab_ws);
  bf16x8 pb[4][2];
  load_P_frags1(Pg,fb,l15,g,pb);
  f32x4 zero={0.f,0.f,0.f,0.f};
  f32x4 cacc[4][4];
  #pragma unroll
  for(int mt=0;mt<4;++mt)
    #pragma unroll
    for(int et=0;et<4;++et) cacc[mt][et]=zero;
  float ksacc[4]={0.f,0.f,0.f,0.f};
  int cur=0;
  STAGE32(Kg, &kstage[0][0], rowbase);
  __syncthreads();                       // drain staging for iter 0
  #pragma unroll 1
  for(int it=0;it<8;++it){
    long n0=rowbase+it*32;
    long np=(it==7)? rowbase : n0+32;    // last iter: dummy re-stage (harmless)
    STAGE32(Kg, &kstage[cur^1][0], np);  // issue next K tile; lands by barrier
    // V raw prefetch (latency hidden under dd-GEMM + exp)
    float vx[4][8];
    #pragma unroll
    for(int et=0;et<4;++et)
      #pragma unroll
      for(int j=0;j<8;++j) vx[et][j]=Vg[(n0+8*g+j)*64+16*et+l15];
    // K a-frags (single bf16) + row sums of squares, from staged LDS
    bf16x8 ka[2][2];
    float dsq[2];
    #pragma unroll
    for(int rt=0;rt<2;++rt){
      float ss=0.f;
      #pragma unroll
      for(int ks=0;ks<2;++ks){
        float x[8]; FRAGREAD(x,&kstage[cur][0],16*rt+l15,ks);
        #pragma unroll
        for(int i=0;i<8;++i) ss=fmaf(x[i],x[i],ss);
        cvt8b(x,ka[rt][ks]);
      }
      ss+=__shfl_xor(ss,16); ss+=__shfl_xor(ss,32);
      dsq[rt]=DSC*ss;
    }
    // dd = K_b @ P_b (1-pass)
    f32x4 dacc[2][4];
    #pragma unroll
    for(int rt=0;rt<2;++rt)
      #pragma unroll
      for(int ft=0;ft<4;++ft) dacc[rt][ft]=zero;
    __builtin_amdgcn_s_setprio(1);
    #pragma unroll
    for(int rt=0;rt<2;++rt)
      #pragma unroll
      for(int ft=0;ft<4;++ft)
        #pragma unroll
        for(int ks=0;ks<2;++ks)
          dacc[rt][ft]=mfma16(ka[rt][ks],pb[ft][ks],dacc[rt][ft]);
    __builtin_amdgcn_s_setprio(0);
    float dg[2][4];
    #pragma unroll
    for(int rt=0;rt<2;++rt)
      #pragma unroll
      for(int r=0;r<4;++r) dg[rt][r]=__shfl(dsq[rt],4*g+r);
    // kp rounded bf16; ksum accumulates the SAME rounded value. Packed b64.
    #pragma unroll
    for(int rt=0;rt<2;++rt)
      #pragma unroll
      for(int ft=0;ft<4;++ft){
        int f=fb+16*ft+l15;
        ushort4 pk;
        unsigned short hvb[4];
        #pragma unroll
        for(int r=0;r<4;++r){
          float kp=fmaf(RATIO,__expf(dacc[rt][ft][r]-dg[rt][r]-stab),REPS);
          bf16 hb=(bf16)kp;
          ksacc[ft]+=(float)hb;
          hvb[r]=__builtin_bit_cast(unsigned short,hb);
        }
        pk.x=hvb[0]; pk.y=hvb[1]; pk.z=hvb[2]; pk.w=hvb[3];
        *(ushort4*)&kpt_h[f*40+16*rt+4*g]=pk;
      }
    // V b-frags (split from prefetched registers)
    bf16x8 vb_h[4], vb_l[4];
    #pragma unroll
    for(int et=0;et<4;++et) split8(vx[et],vb_h[et],vb_l[et]);
    // ctx += kp_b^T @ V (kp single-plane x V split = 2-pass)
    __builtin_amdgcn_s_setprio(1);
    #pragma unroll
    for(int mt=0;mt<4;++mt){
      bf16x8 a_h=*(const bf16x8*)&kpt_h[(fb+16*mt+l15)*40+8*g];
      #pragma unroll
      for(int et=0;et<4;++et){
        cacc[mt][et]=mfma16(a_h,vb_h[et],cacc[mt][et]);
        cacc[mt][et]=mfma16(a_h,vb_l[et],cacc[mt][et]);
      }
    }
    __builtin_amdgcn_s_setprio(0);
    __syncthreads();   // kstage[cur] reads done; staging vmcnt drained
    cur^=1;
  }
  // ---- ksum cross-g reduce (both modes) ----
  float ksred[4];
  #pragma unroll
  for(int ft=0;ft<4;++ft){
    float s=ksacc[ft];
    s+=__shfl_xor(s,16); s+=__shfl_xor(s,32);
    ksred[ft]=s;
  }
  if(mode){
    float* cg=part+((long)ch*BH_+bh)*SLICE_W;
    #pragma unroll
    for(int mt=0;mt<4;++mt)
      #pragma unroll
      for(int et=0;et<4;++et)
        #pragma unroll
        for(int r=0;r<4;++r)
          cg[(fb+16*mt+4*g+r)*64+16*et+l15]=cacc[mt][et][r];
    if(g==0){
      #pragma unroll
      for(int ft=0;ft<4;++ft)
        cg[16384+fb+16*ft+l15]=ksred[ft];
    }
  }else{
    float* cg=ctx_g+(long)bh*16384;
    #pragma unroll
    for(int mt=0;mt<4;++mt)
      #pragma unroll
      for(int et=0;et<4;++et)
        #pragma unroll
        for(int r=0;r<4;++r)
          atomicAdd(&cg[(fb+16*mt+4*g+r)*64+16*et+l15],cacc[mt][et][r]);
    if(g==0){
      #pragma unroll
      for(int ft=0;ft<4;++ft)
        atomicAdd(&ksum_g[bh*256+fb+16*ft+l15],ksred[ft]);
    }
  }
}

// sum the 32 partial slices -> ctx / ksum. grid 1040 x 256.
__global__ void __launch_bounds__(256) redK(const float* __restrict__ part,
    float* __restrict__ ctx_g, float* __restrict__ ksum_g){
  long t=(long)blockIdx.x*256+threadIdx.x;
  const long TOT=(long)BH_*SLICE_W;          // 266240
  for(long o=t;o<TOT;o+=(long)gridDim.x*256){
    int bh=(int)(o/SLICE_W), idx=(int)(o%SLICE_W);
    float s=0.f;
    #pragma unroll 8
    for(int ch=0;ch<32;++ch)
      s+=part[((long)ch*BH_+bh)*SLICE_W+idx];
    if(idx<16384) ctx_g[(long)bh*16384+idx]=s;
    else          ksum_g[bh*256+idx-16384]=s;
  }
}

// fused qp + out. grid = 512: 16 bh * 32 chunks of 256 rows, 4 fat iters of
// 64 rows. SWAPPED dd (dd^T: row=f=16ft+4g+r, col=n=16rt+l15): no dg gather,
// packed ushort4 qpt writes, local 16-reduce + 2 shfls for rowmax/den.
// Q LDS-staged dbuf, single bf16 dd; ctx split; PV unchanged.
__global__ void __launch_bounds__(256,2) qoK(const float* __restrict__ Qg,
    const float* __restrict__ Pg, const float* __restrict__ ctx_g,
    const float* __restrict__ ksum_g, float* __restrict__ outg){
  __shared__ float qstage[2][4096];          // 2 x 16KB staged Q tiles (swizzled)
  __shared__ __align__(16) bf16 qpt[64*264]; // bf16 qp plane, [n][f], stride 264
  __shared__ float rmaxl[4][64];
  __shared__ float denl[4][64];
  int tid=threadIdx.x, w=tid>>6, lane=tid&63, l15=lane&15, g=lane>>4;
  int fb=w*64;
  int bh=blockIdx.x>>5, ch=blockIdx.x&31;
  long rowbase=(long)bh*N_ + ch*256;

  bf16x8 pb[4][2];
  load_P_frags1(Pg,fb,l15,g,pb);
  // ksum for this thread's f set: f = fb+16*ft+4*g+r  (4 consecutive per ft)
  float4 ksv2[4];
  #pragma unroll
  for(int ft=0;ft<4;++ft)
    ksv2[ft]=*(const float4*)&ksum_g[bh*256+fb+16*ft+4*g];
  // ctx b-frags for this wave's e-tile (et = w), split
  bf16x8 cb_h[8], cb_l[8];
  #pragma unroll
  for(int ks=0;ks<8;++ks){
    float x[8];
    #pragma unroll
    for(int j=0;j<8;++j) x[j]=ctx_g[(long)bh*16384+(32*ks+8*g+j)*64+16*w+l15];
    split8(x,cb_h[ks],cb_l[ks]);
  }
  f32x4 zero={0.f,0.f,0.f,0.f};
  int cur=0;
  STAGE64(Qg, &qstage[0][0], rowbase);
  __syncthreads();                     // drain staging for iter 0
  #pragma unroll 1
  for(int it=0;it<4;++it){
    long n0=rowbase+it*64;
    long np=(it==3)? rowbase : n0+64;  // last iter: dummy re-stage (harmless)
    STAGE64(Qg, &qstage[cur^1][0], np);// issue next tile; lands by next barrier
    // dd^T per row-tile rt: dacc[rt][ft][r] = dd[n=16rt+l15][f=16ft+4g+r]
    f32x4 dacc[4][4];
    float dsq[4];
    #pragma unroll
    for(int rt=0;rt<4;++rt){
      bf16x8 qa[2];
      float ss=0.f;
      #pragma unroll
      for(int ks=0;ks<2;++ks){
        float x[8]; FRAGREAD(x,&qstage[cur][0],16*rt+l15,ks);
        #pragma unroll
        for(int i=0;i<8;++i) ss=fmaf(x[i],x[i],ss);
        cvt8b(x,qa[ks]);
      }
      ss+=__shfl_xor(ss,16); ss+=__shfl_xor(ss,32);   // all lanes: full sum
      dsq[rt]=DSC*ss;                                  // diag for n=16rt+l15
      #pragma unroll
      for(int ft=0;ft<4;++ft) dacc[rt][ft]=zero;
      __builtin_amdgcn_s_setprio(1);
      #pragma unroll
      for(int ft=0;ft<4;++ft)
        #pragma unroll
        for(int ks=0;ks<2;++ks)
          dacc[rt][ft]=mfma16(pb[ft][ks],qa[ks],dacc[rt][ft]);  // SWAPPED
      __builtin_amdgcn_s_setprio(0);
    }
    // rowmax per n: local max over 16 (ft,r) + cross-g butterfly
    #pragma unroll
    for(int rt=0;rt<4;++rt){
      float m=-3.4e38f;
      #pragma unroll
      for(int ft=0;ft<4;++ft)
        #pragma unroll
        for(int r=0;r<4;++r) m=fmaxf(m,dacc[rt][ft][r]);
      m=fmaxf(m,__shfl_xor(m,16));
      m=fmaxf(m,__shfl_xor(m,32));
      if(g==0) rmaxl[w][16*rt+l15]=m;
    }
    __syncthreads();   // rowmax planes ready (also fences staging of cur^1)
    // qp (rounded bf16), den partial, packed ushort4 qpt writes
    #pragma unroll
    for(int rt=0;rt<4;++rt){
      int nn=16*rt+l15;
      float rm=fmaxf(fmaxf(rmaxl[0][nn],rmaxl[1][nn]),
                     fmaxf(rmaxl[2][nn],rmaxl[3][nn]));
      float base=dsq[rt]+rm;
      float dp=0.f;
      #pragma unroll
      for(int ft=0;ft<4;++ft){
        unsigned short hvb[4];
        float kw[4]={ksv2[ft].x,ksv2[ft].y,ksv2[ft].z,ksv2[ft].w};
        #pragma unroll
        for(int r=0;r<4;++r){
          float qp=fmaf(RATIO,__expf(dacc[rt][ft][r]-base),REPS);
          bf16 hb=(bf16)qp;
          dp=fmaf((float)hb,kw[r],dp);
          hvb[r]=__builtin_bit_cast(unsigned short,hb);
        }
        ushort4 pk; pk.x=hvb[0]; pk.y=hvb[1]; pk.z=hvb[2]; pk.w=hvb[3];
        *(ushort4*)&qpt[nn*264 + fb+16*ft+4*g]=pk;
      }
      dp+=__shfl_xor(dp,16); dp+=__shfl_xor(dp,32);
      if(g==0) denl[w][nn]=dp;
    }
    __syncthreads();   // qpt + denl ready
    // out = qp_b @ ctx (single-plane qp x split ctx = 2-pass)
    f32x4 oacc[4];
    #pragma unroll
    for(int mt=0;mt<4;++mt) oacc[mt]=zero;
    __builtin_amdgcn_s_setprio(1);
    #pragma unroll
    for(int ks=0;ks<8;++ks)
      #pragma unroll
      for(int mt=0;mt<4;++mt){
        bf16x8 a_h=*(const bf16x8*)&qpt[(16*mt+l15)*264+32*ks+8*g];
        oacc[mt]=mfma16(a_h,cb_h[ks],oacc[mt]);
        oacc[mt]=mfma16(a_h,cb_l[ks],oacc[mt]);
      }
    __builtin_amdgcn_s_setprio(0);
    #pragma unroll
    for(int mt=0;mt<4;++mt)
      #pragma unroll
      for(int r=0;r<4;++r){
        int nn=16*mt+4*g+r;
        float den=denl[0][nn]+denl[1][nn]+denl[2][nn]+denl[3][nn];
        float rden=__builtin_amdgcn_rcpf(den);
        outg[(n0+nn)*64+16*w+l15]=oacc[mt][r]*rden;
      }
    cur^=1;
  }
}

// ---------------- host ----------------

extern "C" void kernel_launch(void* const* d_in, const int* in_sizes, int n_in,
                              void* d_out, int out_size, void* d_ws, size_t ws_size,
                              hipStream_t stream) {
  (void)in_sizes; (void)n_in; (void)out_size;
  const float* q = (const float*)d_in[0];
  const float* k = (const float*)d_in[1];
  const float* v = (const float*)d_in[2];
  const float* P = (const float*)d_in[3];
  float* out = (float*)d_out;

  unsigned* stab = (unsigned*)d_ws;
  float* ctx  = (float*)d_ws + CTX_W;
  float* ksum = (float*)d_ws + KSUM_W;
  float* part = (float*)d_ws + PART_W;

  size_t need = ((size_t)PART_W + (size_t)32*BH_*SLICE_W) * 4;  // ~35.1 MB
  int mode = (ws_size >= need) ? 1 : 0;

  // mode 1: redK fully overwrites ctx/ksum -> only stab header needs zeroing
  if(mode)
    hipLaunchKernelGGL(initK, dim3(1), dim3(256), 0, stream, (unsigned*)d_ws, CTX_W);
  else
    hipLaunchKernelGGL(initK, dim3(256), dim3(256), 0, stream, (unsigned*)d_ws, ZERO_W);
  hipLaunchKernelGGL(stabK, dim3(512), dim3(256), 0, stream, k, P, stab);
  hipLaunchKernelGGL(ctxK, dim3(512), dim3(256), 0, stream, k, v, P, stab,
                     ctx, ksum, part, mode);
  if(mode)
    hipLaunchKernelGGL(redK, dim3(1040), dim3(256), 0, stream, part, ctx, ksum);
  hipLaunchKernelGGL(qoK, dim3(512), dim3(256), 0, stream, q, P, ctx, ksum, out);
}

// Round 21
// 101.786 us; speedup vs baseline: 1.2839x; 1.0394x over previous
//
#include <hip/hip_runtime.h>

// Performer (FAVOR+) attention, MI355X, split-bf16 MFMA.
// B=2 H=8 N=8192 D=64 F=256; rows R = 131072.
// Round 21 (residual bundle; ctxK/qoK unchanged from r20):
//  * stabK: grid 512->256 (8 iters) — P-frag fixed cost amortized 2x; setprio.
//  * redK: float4 loads/stores (grid 260, 4 outputs/thread) — 4x fewer
//    load instructions at identical bytes; 16384%4==0 so no straddle.
// History: r17 DPP butterflies, r18 single-bf16 features + setprio,
// r20 swapped-operand dd^T in qoK. absmax must stay 3.662e-4 (no math change).

typedef __bf16 bf16;
typedef __bf16 bf16x8 __attribute__((ext_vector_type(8)));
typedef _Float16 f16;
typedef f16 f16x8 __attribute__((ext_vector_type(8)));
typedef float f32x4 __attribute__((ext_vector_type(4)));

#define N_    8192
#define BH_   16
#define NRM   0.35355339059327379f   // 64^-0.25
#define RATIO 0.0625f                // 256^-0.5
#define DSC   0.0625f                // 0.5*NRM^2
#define REPS  6.25e-6f               // RATIO*1e-4

#define CTX_W  16
#define KSUM_W (CTX_W + BH_*256*64)     // 262160
#define ZERO_W (KSUM_W + BH_*256)       // 266256
#define SLICE_W 16640                   // 16384 ctx + 256 ksum per (bh,ch)
#define PART_W  ZERO_W                  // partials start here (32*16*16640 w)

static __device__ __forceinline__ unsigned mapmax(float x){
  unsigned u=__float_as_uint(x); return (u&0x80000000u)? ~u : (u|0x80000000u);
}
static __device__ __forceinline__ float unmapmax(unsigned u){
  return __uint_as_float((u&0x80000000u)? (u&0x7fffffffu) : ~u);
}
static __device__ __forceinline__ f32x4 mfma16(bf16x8 a, bf16x8 b, f32x4 c){
  return __builtin_amdgcn_mfma_f32_16x16x32_bf16(a,b,c,0,0,0);
}
static __device__ __forceinline__ f32x4 mfma16h(f16x8 a, f16x8 b, f32x4 c){
  return __builtin_amdgcn_mfma_f32_16x16x32_f16(a,b,c,0,0,0);
}
static __device__ __forceinline__ void ld8(const float* __restrict__ p, float* x){
  float4 a=*(const float4*)p; float4 b=*(const float4*)(p+4);
  x[0]=a.x; x[1]=a.y; x[2]=a.z; x[3]=a.w; x[4]=b.x; x[5]=b.y; x[6]=b.z; x[7]=b.w;
}
static __device__ __forceinline__ void split8(const float* x, bf16x8& h, bf16x8& l){
  #pragma unroll
  for(int i=0;i<8;++i){ bf16 hi=(bf16)x[i]; h[i]=hi; l[i]=(bf16)(x[i]-(float)hi); }
}
static __device__ __forceinline__ void cvt8b(const float* x, bf16x8& h){
  #pragma unroll
  for(int i=0;i<8;++i) h[i]=(bf16)x[i];
}
static __device__ __forceinline__ void cvt8h(const float* x, f16x8& h){
  #pragma unroll
  for(int i=0;i<8;++i) h[i]=(f16)x[i];
}
static __device__ __forceinline__ void gload16(const float* g, float* l){
  __builtin_amdgcn_global_load_lds(
      (const __attribute__((address_space(1))) unsigned*)g,
      (__attribute__((address_space(3))) unsigned*)l, 16, 0, 0);
}
// P-hat (NRM*P) b-fragments, SINGLE bf16 plane: [ft 0..3][ks 0..1]
static __device__ __forceinline__ void load_P_frags1(const float* __restrict__ Pg,
    int fb, int l15, int g, bf16x8 (&pb)[4][2]){
  #pragma unroll
  for(int ft=0;ft<4;++ft)
    #pragma unroll
    for(int ks=0;ks<2;++ks){
      float x[8]; ld8(&Pg[(fb+16*ft+l15)*64+32*ks+8*g],x);
      #pragma unroll
      for(int i=0;i<8;++i) x[i]*=NRM;
      cvt8b(x,pb[ft][ks]);
    }
}

// stage 32 rows x 64 floats from Xg into LDS buf, source XOR-swizzled by
// row&15 so fragment-pattern b128 reads are conflict-free (r9 pattern).
#define STAGE32(Xg, bufptr, n0s) do{                                      \
    int u0_=tid, u1_=tid+256;                                             \
    int r0_=u0_>>4, c0_=u0_&15, r1_=u1_>>4, c1_=u1_&15;                   \
    gload16((Xg)+((n0s)+r0_)*64+((c0_^(r0_&15))<<2), (bufptr)+u0_*4);     \
    gload16((Xg)+((n0s)+r1_)*64+((c1_^(r1_&15))<<2), (bufptr)+u1_*4);     \
  }while(0)
// stage 64 rows x 64 floats (qoK fat iters)
#define STAGE64(Xg, bufptr, n0s) do{                                      \
    _Pragma("unroll")                                                     \
    for(int ii_=0;ii_<4;++ii_){                                           \
      int u_=tid+256*ii_;                                                 \
      int r_=u_>>4, c_=u_&15;                                             \
      gload16((Xg)+((n0s)+r_)*64+((c_^(r_&15))<<2), (bufptr)+u_*4);       \
    }                                                                     \
  }while(0)
// x[8] <- staged row rr, k-chunk ks (two swizzled b128 reads)
#define FRAGREAD(xv, bufptr, rr, ksv) do{                                 \
    int cc0_=(8*(ksv)+2*g)^((rr)&15);                                     \
    int cc1_=cc0_^1;                                                      \
    float4 a_=*(const float4*)((bufptr)+(rr)*64+cc0_*4);                  \
    float4 b_=*(const float4*)((bufptr)+(rr)*64+cc1_*4);                  \
    xv[0]=a_.x; xv[1]=a_.y; xv[2]=a_.z; xv[3]=a_.w;                       \
    xv[4]=b_.x; xv[5]=b_.y; xv[6]=b_.z; xv[7]=b_.w;                       \
  }while(0)

// ---------------- kernels ----------------

__global__ void __launch_bounds__(256) initK(unsigned* ws, int n){
  for(int i=blockIdx.x*256+threadIdx.x;i<n;i+=gridDim.x*256) ws[i]=0u;
}

// global max of dd_k (single-f16). grid 256, 8 iters of 64 rows (P amortized).
__global__ void __launch_bounds__(256) stabK(const float* __restrict__ Kg,
                                             const float* __restrict__ Pg,
                                             unsigned* __restrict__ stab_ws){
  __shared__ float red[4];
  int tid=threadIdx.x, w=tid>>6, lane=tid&63, l15=lane&15, g=lane>>4;
  int fb=w*64;
  f16x8 pb[4][2];
  #pragma unroll
  for(int ft=0;ft<4;++ft)
    #pragma unroll
    for(int ks=0;ks<2;++ks){
      float x[8]; ld8(&Pg[(fb+16*ft+l15)*64+32*ks+8*g],x);
      #pragma unroll
      for(int i=0;i<8;++i) x[i]*=NRM;
      cvt8h(x,pb[ft][ks]);
    }
  float m=-3.4e38f;
  long base=(long)blockIdx.x*512;
  f32x4 zero={0.f,0.f,0.f,0.f};
  #pragma unroll 1
  for(int it=0;it<8;++it){
    long row0=base+it*64;
    f16x8 ka[4][2];
    #pragma unroll
    for(int rt=0;rt<4;++rt)
      #pragma unroll
      for(int ks=0;ks<2;++ks){
        float x[8]; ld8(&Kg[(row0+16*rt+l15)*64+32*ks+8*g],x);
        cvt8h(x,ka[rt][ks]);
      }
    f32x4 acc[4][4];
    #pragma unroll
    for(int rt=0;rt<4;++rt)
      #pragma unroll
      for(int ft=0;ft<4;++ft) acc[rt][ft]=zero;
    __builtin_amdgcn_s_setprio(1);
    #pragma unroll
    for(int rt=0;rt<4;++rt)
      #pragma unroll
      for(int ft=0;ft<4;++ft)
        #pragma unroll
        for(int ks=0;ks<2;++ks)
          acc[rt][ft]=mfma16h(ka[rt][ks],pb[ft][ks],acc[rt][ft]);
    __builtin_amdgcn_s_setprio(0);
    #pragma unroll
    for(int rt=0;rt<4;++rt)
      #pragma unroll
      for(int ft=0;ft<4;++ft)
        #pragma unroll
        for(int r=0;r<4;++r) m=fmaxf(m,acc[rt][ft][r]);
  }
  #pragma unroll
  for(int off=1;off<64;off<<=1) m=fmaxf(m,__shfl_xor(m,off));
  if(lane==0) red[w]=m;
  __syncthreads();
  if(tid==0){
    m=fmaxf(fmaxf(red[0],red[1]),fmaxf(red[2],red[3]));
    atomicMax(stab_ws,mapmax(m));
  }
}

// kp + ctx/ksum accumulation. grid = 512: 16 bh * 32 chunks of 256 rows,
// 8 iters. K LDS-staged dbuf, SINGLE bf16 in dd (1-pass); V reg-prefetched
// (split); P single bf16. kpt writes packed b64. UNCHANGED from r20.
__global__ void __launch_bounds__(256,2) ctxK(const float* __restrict__ Kg,
    const float* __restrict__ Vg, const float* __restrict__ Pg,
    const unsigned* __restrict__ stab_ws, float* __restrict__ ctx_g,
    float* __restrict__ ksum_g, float* __restrict__ part, int mode){
  __shared__ __align__(16) bf16 kpt_h[256*40];   // 20KB
  __shared__ float kstage[2][2048];              // 2 x 8KB staged K tiles
  int tid=threadIdx.x, w=tid>>6, lane=tid&63, l15=lane&15, g=lane>>4;
  int fb=w*64;
  int bh=blockIdx.x>>5, ch=blockIdx.x&31;
  long rowbase=(long)bh*N_ + ch*256;
  float stab=unmapmax(*stab_ws);
  bf16x8 pb[4][2];
  load_P_frags1(Pg,fb,l15,g,pb);
  f32x4 zero={0.f,0.f,0.f,0.f};
  f32x4 cacc[4][4];
  #pragma unroll
  for(int mt=0;mt<4;++mt)
    #pragma unroll
    for(int et=0;et<4;++et) cacc[mt][et]=zero;
  float ksacc[4]={0.f,0.f,0.f,0.f};
  int cur=0;
  STAGE32(Kg, &kstage[0][0], rowbase);
  __syncthreads();                       // drain staging for iter 0
  #pragma unroll 1
  for(int it=0;it<8;++it){
    long n0=rowbase+it*32;
    long np=(it==7)? rowbase : n0+32;    // last iter: dummy re-stage (harmless)
    STAGE32(Kg, &kstage[cur^1][0], np);  // issue next K tile; lands by barrier
    // V raw prefetch (latency hidden under dd-GEMM + exp)
    float vx[4][8];
    #pragma unroll
    for(int et=0;et<4;++et)
      #pragma unroll
      for(int j=0;j<8;++j) vx[et][j]=Vg[(n0+8*g+j)*64+16*et+l15];
    // K a-frags (single bf16) + row sums of squares, from staged LDS
    bf16x8 ka[2][2];
    float dsq[2];
    #pragma unroll
    for(int rt=0;rt<2;++rt){
      float ss=0.f;
      #pragma unroll
      for(int ks=0;ks<2;++ks){
        float x[8]; FRAGREAD(x,&kstage[cur][0],16*rt+l15,ks);
        #pragma unroll
        for(int i=0;i<8;++i) ss=fmaf(x[i],x[i],ss);
        cvt8b(x,ka[rt][ks]);
      }
      ss+=__shfl_xor(ss,16); ss+=__shfl_xor(ss,32);
      dsq[rt]=DSC*ss;
    }
    // dd = K_b @ P_b (1-pass)
    f32x4 dacc[2][4];
    #pragma unroll
    for(int rt=0;rt<2;++rt)
      #pragma unroll
      for(int ft=0;ft<4;++ft) dacc[rt][ft]=zero;
    __builtin_amdgcn_s_setprio(1);
    #pragma unroll
    for(int rt=0;rt<2;++rt)
      #pragma unroll
      for(int ft=0;ft<4;++ft)
        #pragma unroll
        for(int ks=0;ks<2;++ks)
          dacc[rt][ft]=mfma16(ka[rt][ks],pb[ft][ks],dacc[rt][ft]);
    __builtin_amdgcn_s_setprio(0);
    float dg[2][4];
    #pragma unroll
    for(int rt=0;rt<2;++rt)
      #pragma unroll
      for(int r=0;r<4;++r) dg[rt][r]=__shfl(dsq[rt],4*g+r);
    // kp rounded bf16; ksum accumulates the SAME rounded value. Packed b64.
    #pragma unroll
    for(int rt=0;rt<2;++rt)
      #pragma unroll
      for(int ft=0;ft<4;++ft){
        int f=fb+16*ft+l15;
        ushort4 pk;
        unsigned short hvb[4];
        #pragma unroll
        for(int r=0;r<4;++r){
          float kp=fmaf(RATIO,__expf(dacc[rt][ft][r]-dg[rt][r]-stab),REPS);
          bf16 hb=(bf16)kp;
          ksacc[ft]+=(float)hb;
          hvb[r]=__builtin_bit_cast(unsigned short,hb);
        }
        pk.x=hvb[0]; pk.y=hvb[1]; pk.z=hvb[2]; pk.w=hvb[3];
        *(ushort4*)&kpt_h[f*40+16*rt+4*g]=pk;
      }
    // V b-frags (split from prefetched registers)
    bf16x8 vb_h[4], vb_l[4];
    #pragma unroll
    for(int et=0;et<4;++et) split8(vx[et],vb_h[et],vb_l[et]);
    // ctx += kp_b^T @ V (kp single-plane x V split = 2-pass)
    __builtin_amdgcn_s_setprio(1);
    #pragma unroll
    for(int mt=0;mt<4;++mt){
      bf16x8 a_h=*(const bf16x8*)&kpt_h[(fb+16*mt+l15)*40+8*g];
      #pragma unroll
      for(int et=0;et<4;++et){
        cacc[mt][et]=mfma16(a_h,vb_h[et],cacc[mt][et]);
        cacc[mt][et]=mfma16(a_h,vb_l[et],cacc[mt][et]);
      }
    }
    __builtin_amdgcn_s_setprio(0);
    __syncthreads();   // kstage[cur] reads done; staging vmcnt drained
    cur^=1;
  }
  // ---- ksum cross-g reduce (both modes) ----
  float ksred[4];
  #pragma unroll
  for(int ft=0;ft<4;++ft){
    float s=ksacc[ft];
    s+=__shfl_xor(s,16); s+=__shfl_xor(s,32);
    ksred[ft]=s;
  }
  if(mode){
    float* cg=part+((long)ch*BH_+bh)*SLICE_W;
    #pragma unroll
    for(int mt=0;mt<4;++mt)
      #pragma unroll
      for(int et=0;et<4;++et)
        #pragma unroll
        for(int r=0;r<4;++r)
          cg[(fb+16*mt+4*g+r)*64+16*et+l15]=cacc[mt][et][r];
    if(g==0){
      #pragma unroll
      for(int ft=0;ft<4;++ft)
        cg[16384+fb+16*ft+l15]=ksred[ft];
    }
  }else{
    float* cg=ctx_g+(long)bh*16384;
    #pragma unroll
    for(int mt=0;mt<4;++mt)
      #pragma unroll
      for(int et=0;et<4;++et)
        #pragma unroll
        for(int r=0;r<4;++r)
          atomicAdd(&cg[(fb+16*mt+4*g+r)*64+16*et+l15],cacc[mt][et][r]);
    if(g==0){
      #pragma unroll
      for(int ft=0;ft<4;++ft)
        atomicAdd(&ksum_g[bh*256+fb+16*ft+l15],ksred[ft]);
    }
  }
}

// sum the 32 partial slices -> ctx / ksum. grid 260 x 256, float4 per thread.
// SLICE_W%4==0 and 16384%4==0 so a float4 never straddles ctx/ksum.
__global__ void __launch_bounds__(256) redK(const float* __restrict__ part,
    float* __restrict__ ctx_g, float* __restrict__ ksum_g){
  const long TOT4=(long)BH_*(SLICE_W/4);     // 66560 float4 outputs
  long t=(long)blockIdx.x*256+threadIdx.x;
  for(long o=t;o<TOT4;o+=(long)gridDim.x*256){
    int bh=(int)(o/(SLICE_W/4)), idx4=(int)(o%(SLICE_W/4));
    float4 s=make_float4(0.f,0.f,0.f,0.f);
    #pragma unroll 8
    for(int ch=0;ch<32;++ch){
      float4 v=*(const float4*)&part[((long)ch*BH_+bh)*SLICE_W+idx4*4];
      s.x+=v.x; s.y+=v.y; s.z+=v.z; s.w+=v.w;
    }
    int idx=idx4*4;
    if(idx<16384) *(float4*)&ctx_g[(long)bh*16384+idx]=s;
    else          *(float4*)&ksum_g[bh*256+idx-16384]=s;
  }
}

// fused qp + out. grid = 512: 16 bh * 32 chunks of 256 rows, 4 fat iters of
// 64 rows. SWAPPED dd (dd^T: row=f=16ft+4g+r, col=n=16rt+l15): no dg gather,
// packed ushort4 qpt writes, local 16-reduce + 2 shfls for rowmax/den.
// Q LDS-staged dbuf, single bf16 dd; ctx split; PV unchanged. = r20.
__global__ void __launch_bounds__(256,2) qoK(const float* __restrict__ Qg,
    const float* __restrict__ Pg, const float* __restrict__ ctx_g,
    const float* __restrict__ ksum_g, float* __restrict__ outg){
  __shared__ float qstage[2][4096];          // 2 x 16KB staged Q tiles (swizzled)
  __shared__ __align__(16) bf16 qpt[64*264]; // bf16 qp plane, [n][f], stride 264
  __shared__ float rmaxl[4][64];
  __shared__ float denl[4][64];
  int tid=threadIdx.x, w=tid>>6, lane=tid&63, l15=lane&15, g=lane>>4;
  int fb=w*64;
  int bh=blockIdx.x>>5, ch=blockIdx.x&31;
  long rowbase=(long)bh*N_ + ch*256;

  bf16x8 pb[4][2];
  load_P_frags1(Pg,fb,l15,g,pb);
  // ksum for this thread's f set: f = fb+16*ft+4*g+r  (4 consecutive per ft)
  float4 ksv2[4];
  #pragma unroll
  for(int ft=0;ft<4;++ft)
    ksv2[ft]=*(const float4*)&ksum_g[bh*256+fb+16*ft+4*g];
  // ctx b-frags for this wave's e-tile (et = w), split
  bf16x8 cb_h[8], cb_l[8];
  #pragma unroll
  for(int ks=0;ks<8;++ks){
    float x[8];
    #pragma unroll
    for(int j=0;j<8;++j) x[j]=ctx_g[(long)bh*16384+(32*ks+8*g+j)*64+16*w+l15];
    split8(x,cb_h[ks],cb_l[ks]);
  }
  f32x4 zero={0.f,0.f,0.f,0.f};
  int cur=0;
  STAGE64(Qg, &qstage[0][0], rowbase);
  __syncthreads();                     // drain staging for iter 0
  #pragma unroll 1
  for(int it=0;it<4;++it){
    long n0=rowbase+it*64;
    long np=(it==3)? rowbase : n0+64;  // last iter: dummy re-stage (harmless)
    STAGE64(Qg, &qstage[cur^1][0], np);// issue next tile; lands by next barrier
    // dd^T per row-tile rt: dacc[rt][ft][r] = dd[n=16rt+l15][f=16ft+4g+r]
    f32x4 dacc[4][4];
    float dsq[4];
    #pragma unroll
    for(int rt=0;rt<4;++rt){
      bf16x8 qa[2];
      float ss=0.f;
      #pragma unroll
      for(int ks=0;ks<2;++ks){
        float x[8]; FRAGREAD(x,&qstage[cur][0],16*rt+l15,ks);
        #pragma unroll
        for(int i=0;i<8;++i) ss=fmaf(x[i],x[i],ss);
        cvt8b(x,qa[ks]);
      }
      ss+=__shfl_xor(ss,16); ss+=__shfl_xor(ss,32);   // all lanes: full sum
      dsq[rt]=DSC*ss;                                  // diag for n=16rt+l15
      #pragma unroll
      for(int ft=0;ft<4;++ft) dacc[rt][ft]=zero;
      __builtin_amdgcn_s_setprio(1);
      #pragma unroll
      for(int ft=0;ft<4;++ft)
        #pragma unroll
        for(int ks=0;ks<2;++ks)
          dacc[rt][ft]=mfma16(pb[ft][ks],qa[ks],dacc[rt][ft]);  // SWAPPED
      __builtin_amdgcn_s_setprio(0);
    }
    // rowmax per n: local max over 16 (ft,r) + cross-g butterfly
    #pragma unroll
    for(int rt=0;rt<4;++rt){
      float m=-3.4e38f;
      #pragma unroll
      for(int ft=0;ft<4;++ft)
        #pragma unroll
        for(int r=0;r<4;++r) m=fmaxf(m,dacc[rt][ft][r]);
      m=fmaxf(m,__shfl_xor(m,16));
      m=fmaxf(m,__shfl_xor(m,32));
      if(g==0) rmaxl[w][16*rt+l15]=m;
    }
    __syncthreads();   // rowmax planes ready (also fences staging of cur^1)
    // qp (rounded bf16), den partial, packed ushort4 qpt writes
    #pragma unroll
    for(int rt=0;rt<4;++rt){
      int nn=16*rt+l15;
      float rm=fmaxf(fmaxf(rmaxl[0][nn],rmaxl[1][nn]),
                     fmaxf(rmaxl[2][nn],rmaxl[3][nn]));
      float base=dsq[rt]+rm;
      float dp=0.f;
      #pragma unroll
      for(int ft=0;ft<4;++ft){
        unsigned short hvb[4];
        float kw[4]={ksv2[ft].x,ksv2[ft].y,ksv2[ft].z,ksv2[ft].w};
        #pragma unroll
        for(int r=0;r<4;++r){
          float qp=fmaf(RATIO,__expf(dacc[rt][ft][r]-base),REPS);
          bf16 hb=(bf16)qp;
          dp=fmaf((float)hb,kw[r],dp);
          hvb[r]=__builtin_bit_cast(unsigned short,hb);
        }
        ushort4 pk; pk.x=hvb[0]; pk.y=hvb[1]; pk.z=hvb[2]; pk.w=hvb[3];
        *(ushort4*)&qpt[nn*264 + fb+16*ft+4*g]=pk;
      }
      dp+=__shfl_xor(dp,16); dp+=__shfl_xor(dp,32);
      if(g==0) denl[w][nn]=dp;
    }
    __syncthreads();   // qpt + denl ready
    // out = qp_b @ ctx (single-plane qp x split ctx = 2-pass)
    f32x4 oacc[4];
    #pragma unroll
    for(int mt=0;mt<4;++mt) oacc[mt]=zero;
    __builtin_amdgcn_s_setprio(1);
    #pragma unroll
    for(int ks=0;ks<8;++ks)
      #pragma unroll
      for(int mt=0;mt<4;++mt){
        bf16x8 a_h=*(const bf16x8*)&qpt[(16*mt+l15)*264+32*ks+8*g];
        oacc[mt]=mfma16(a_h,cb_h[ks],oacc[mt]);
        oacc[mt]=mfma16(a_h,cb_l[ks],oacc[mt]);
      }
    __builtin_amdgcn_s_setprio(0);
    #pragma unroll
    for(int mt=0;mt<4;++mt)
      #pragma unroll
      for(int r=0;r<4;++r){
        int nn=16*mt+4*g+r;
        float den=denl[0][nn]+denl[1][nn]+denl[2][nn]+denl[3][nn];
        float rden=__builtin_amdgcn_rcpf(den);
        outg[(n0+nn)*64+16*w+l15]=oacc[mt][r]*rden;
      }
    cur^=1;
  }
}

// ---------------- host ----------------

extern "C" void kernel_launch(void* const* d_in, const int* in_sizes, int n_in,
                              void* d_out, int out_size, void* d_ws, size_t ws_size,
                              hipStream_t stream) {
  (void)in_sizes; (void)n_in; (void)out_size;
  const float* q = (const float*)d_in[0];
  const float* k = (const float*)d_in[1];
  const float* v = (const float*)d_in[2];
  const float* P = (const float*)d_in[3];
  float* out = (float*)d_out;

  unsigned* stab = (unsigned*)d_ws;
  float* ctx  = (float*)d_ws + CTX_W;
  float* ksum = (float*)d_ws + KSUM_W;
  float* part = (float*)d_ws + PART_W;

  size_t need = ((size_t)PART_W + (size_t)32*BH_*SLICE_W) * 4;  // ~35.1 MB
  int mode = (ws_size >= need) ? 1 : 0;

  // mode 1: redK fully overwrites ctx/ksum -> only stab header needs zeroing
  if(mode)
    hipLaunchKernelGGL(initK, dim3(1), dim3(256), 0, stream, (unsigned*)d_ws, CTX_W);
  else
    hipLaunchKernelGGL(initK, dim3(256), dim3(256), 0, stream, (unsigned*)d_ws, ZERO_W);
  hipLaunchKernelGGL(stabK, dim3(256), dim3(256), 0, stream, k, P, stab);
  hipLaunchKernelGGL(ctxK, dim3(512), dim3(256), 0, stream, k, v, P, stab,
                     ctx, ksum, part, mode);
  if(mode)
    hipLaunchKernelGGL(redK, dim3(260), dim3(256), 0, stream, part, ctx, ksum);
  hipLaunchKernelGGL(qoK, dim3(512), dim3(256), 0, stream, q, P, ctx, ksum, out);
}